// Round 9
// baseline (811.800 us; speedup 1.0000x reference)
//
#include <hip/hip_runtime.h>

typedef unsigned short u16;
typedef __bf16 bf16x8 __attribute__((ext_vector_type(8)));
typedef float f32x4 __attribute__((ext_vector_type(4)));

#define R1 32768   // B*S*NS
#define NBS 1024   // B*S
#define DD 768

__device__ __forceinline__ float bf2f(u16 u){
  union { unsigned int u; float f; } v; v.u = ((unsigned int)u) << 16; return v.f;
}
__device__ __forceinline__ u16 f2bf(float f){
  union { float f; unsigned int u; } v; v.f = f;
  unsigned int r = (v.u + 0x7FFFu + ((v.u >> 16) & 1u)) >> 16;
  return (u16)r;
}
__device__ __forceinline__ float gelu_f(float x){
  return 0.5f * x * (1.0f + erff(x * 0.70710678118654752f));
}
__device__ __forceinline__ void gload16(const u16* g, u16* l){
  __builtin_amdgcn_global_load_lds(
      (const __attribute__((address_space(1))) void*)g,
      (__attribute__((address_space(3))) void*)l, 16, 0, 0);
}

enum { EPI_G1 = 0, EPI_GELU_SPLIT = 2, EPI_BIAS_SPLIT = 3, EPI_F32 = 4 };

// C = A @ Bw^T with split-precision operands. Tile 128x128, BK=32, 4 waves.
// XCD-bijective block swizzle; global_load_lds width-16 staging, LDS writes
// linear with pre-swizzled GLOBAL source cols + XOR-swizzled reads (T2).
// 3-buffer distance-2 pipeline with counted vmcnt (T4).
template<int EPI, int ASPLIT, int WSPLIT>
__global__ __launch_bounds__(256)
void gemm_bt(const u16* __restrict__ Ah, const u16* __restrict__ Al, int lda,
             const u16* __restrict__ Bh, const u16* __restrict__ Bl, int K,
             u16* __restrict__ Ch, u16* __restrict__ Cl, float* __restrict__ Cf,
             const float* __restrict__ bias, const float* __restrict__ w01,
             const float* __restrict__ bias2)
{
  constexpr int NT = 2 + ASPLIT + WSPLIT;
  constexpr int LPS = NT * 2;                      // stage loads per wave
  __shared__ __align__(16) u16 smem[3 * NT * 4096];

  const int nwg = gridDim.x;            // multiple of 8
  const int xcd = blockIdx.x & 7;
  const int wg = xcd * (nwg >> 3) + (blockIdx.x >> 3);
  const int brow = wg / 6, bcol = wg - brow * 6;
  const int row0 = brow << 7;
  const int col0 = bcol << 7;

  const int t = threadIdx.x;
  const int lane = t & 63;
  const int wv = t >> 6;
  const int wr = (wv >> 1) << 6;
  const int wc = (wv & 1) << 6;
  const int r16 = lane & 15;
  const int kg = lane >> 4;

  f32x4 acc[4][4];
#pragma unroll
  for (int m = 0; m < 4; ++m)
#pragma unroll
    for (int n = 0; n < 4; ++n) acc[m][n] = (f32x4){0.f, 0.f, 0.f, 0.f};

  const int c0 = wv * 2, c1 = c0 + 1;
  const int srow = lane >> 2;
  const int scol = (((lane & 3) ^ ((srow >> 1) & 3)) << 3);
  const u16* gAh0 = Ah + (size_t)(row0 + c0 * 16 + srow) * lda + scol;
  const u16* gAh1 = Ah + (size_t)(row0 + c1 * 16 + srow) * lda + scol;
  const u16* gBh0 = Bh + (size_t)(col0 + c0 * 16 + srow) * K + scol;
  const u16* gBh1 = Bh + (size_t)(col0 + c1 * 16 + srow) * K + scol;
  const u16* gAl0 = ASPLIT ? Al + (size_t)(row0 + c0 * 16 + srow) * lda + scol : nullptr;
  const u16* gAl1 = ASPLIT ? Al + (size_t)(row0 + c1 * 16 + srow) * lda + scol : nullptr;
  const u16* gBl0 = WSPLIT ? Bl + (size_t)(col0 + c0 * 16 + srow) * K + scol : nullptr;
  const u16* gBl1 = WSPLIT ? Bl + (size_t)(col0 + c1 * 16 + srow) * K + scol : nullptr;
  const int o0 = c0 * 512, o1 = c1 * 512;

  auto stage = [&](int kt, int buf){
    const int k0 = kt << 5;
    u16* tb = smem + buf * (NT * 4096);
    u16* AsH = tb;
    u16* BsH = tb + (1 + ASPLIT) * 4096;
    gload16(gAh0 + k0, AsH + o0);
    gload16(gAh1 + k0, AsH + o1);
    gload16(gBh0 + k0, BsH + o0);
    gload16(gBh1 + k0, BsH + o1);
    if constexpr (ASPLIT){
      u16* AsL = tb + 4096;
      gload16(gAl0 + k0, AsL + o0);
      gload16(gAl1 + k0, AsL + o1);
    }
    if constexpr (WSPLIT){
      u16* BsL = tb + (2 + ASPLIT) * 4096;
      gload16(gBl0 + k0, BsL + o0);
      gload16(gBl1 + k0, BsL + o1);
    }
  };

  const int kgsw = ((kg ^ ((r16 >> 1) & 3)) << 3);

  auto compute = [&](int buf){
    u16* tb = smem + buf * (NT * 4096);
    u16* AsH = tb;
    u16* AsL = tb + 4096;
    u16* BsH = tb + (1 + ASPLIT) * 4096;
    u16* BsL = tb + (2 + ASPLIT) * 4096;
    bf16x8 afh[4], bqh[4], afl[4], bql[4];
#pragma unroll
    for (int m = 0; m < 4; ++m)
      afh[m] = __builtin_bit_cast(bf16x8, *(const int4*)&AsH[(wr + m * 16 + r16) * 32 + kgsw]);
#pragma unroll
    for (int n = 0; n < 4; ++n)
      bqh[n] = __builtin_bit_cast(bf16x8, *(const int4*)&BsH[(wc + n * 16 + r16) * 32 + kgsw]);
    if constexpr (ASPLIT)
#pragma unroll
      for (int m = 0; m < 4; ++m)
        afl[m] = __builtin_bit_cast(bf16x8, *(const int4*)&AsL[(wr + m * 16 + r16) * 32 + kgsw]);
    if constexpr (WSPLIT)
#pragma unroll
      for (int n = 0; n < 4; ++n)
        bql[n] = __builtin_bit_cast(bf16x8, *(const int4*)&BsL[(wc + n * 16 + r16) * 32 + kgsw]);
#pragma unroll
    for (int m = 0; m < 4; ++m)
#pragma unroll
      for (int n = 0; n < 4; ++n){
        acc[m][n] = __builtin_amdgcn_mfma_f32_16x16x32_bf16(afh[m], bqh[n], acc[m][n], 0, 0, 0);
        if constexpr (WSPLIT)
          acc[m][n] = __builtin_amdgcn_mfma_f32_16x16x32_bf16(afh[m], bql[n], acc[m][n], 0, 0, 0);
        if constexpr (ASPLIT)
          acc[m][n] = __builtin_amdgcn_mfma_f32_16x16x32_bf16(afl[m], bqh[n], acc[m][n], 0, 0, 0);
      }
  };

  const int nkt = K >> 5;
  stage(0, 0);
  stage(1, 1);
  int cur = 0;
  for (int kt = 0; kt < nkt - 1; ++kt){
    asm volatile("s_waitcnt vmcnt(%0) lgkmcnt(0)" :: "i"(LPS) : "memory");
    __builtin_amdgcn_s_barrier();
    asm volatile("" ::: "memory");
    const int nx = (cur == 0) ? 2 : cur - 1;   // (cur+2)%3
    if (kt + 2 < nkt) stage(kt + 2, nx);
    compute(cur);
    cur = (cur == 2) ? 0 : cur + 1;
  }
  asm volatile("s_waitcnt vmcnt(0) lgkmcnt(0)" ::: "memory");
  __builtin_amdgcn_s_barrier();
  asm volatile("" ::: "memory");
  compute(cur);

#pragma unroll
  for (int m = 0; m < 4; ++m){
#pragma unroll
    for (int r = 0; r < 4; ++r){
      const int row = row0 + wr + m * 16 + kg * 4 + r;
      float rw0 = 0.f, rw1 = 0.f;
      if (EPI == EPI_G1){ rw0 = w01[2 * row]; rw1 = w01[2 * row + 1]; }
#pragma unroll
      for (int n = 0; n < 4; ++n){
        const int col = col0 + wc + n * 16 + r16;
        const size_t idx = (size_t)row * DD + col;
        float v = acc[m][n][r];
        if (EPI == EPI_G1){
          v += rw0 * bias[col] + rw1 * bias2[col];
          const u16 h = f2bf(v);
          Ch[idx] = h; Cl[idx] = f2bf(v - bf2f(h));
        } else if (EPI == EPI_GELU_SPLIT){
          v = gelu_f(v + bias[col]);
          const u16 h = f2bf(v);
          Ch[idx] = h; Cl[idx] = f2bf(v - bf2f(h));
        } else if (EPI == EPI_BIAS_SPLIT){
          v = v + bias[col];
          const u16 h = f2bf(v);
          Ch[idx] = h; Cl[idx] = f2bf(v - bf2f(h));
        } else { // EPI_F32
          Cf[idx] = v;
        }
      }
    }
  }
}

// ---- fused G2 + LN + energy + softmax + span (one block per bs group) ------
// inter = gelu(comp @ Wi^T + ib) + comp; h = LN(inter)*g+lnb; e = h.ew;
// span = softmax(e) @ h. tbuf/h never hit HBM.
// Block: 32 rows x 768 cols. Wave (b,hh): rows b*16..+16, cols hh*384..+384.
__global__ __launch_bounds__(256, 1)
void k_g2span(const u16* __restrict__ compH, const u16* __restrict__ compL,
              const u16* __restrict__ WiH, const float* __restrict__ ib,
              const float* __restrict__ g, const float* __restrict__ lnb,
              const float* __restrict__ ew,
              float* __restrict__ span, u16* __restrict__ spanH,
              u16* __restrict__ spanL)
{
  __shared__ __align__(16) u16 smem[2 * 25600];   // [B 24576 | A 1024] x 2 buffers
  const int bs = blockIdx.x;
  const int t = threadIdx.x, lane = t & 63, wv = t >> 6;
  const int b = wv & 1;           // row band
  const int hh = wv >> 1;         // col half
  const int r16 = lane & 15, kg = lane >> 4;
  const int srow = lane >> 2, slot = lane & 3;
  const int kgsw = ((kg ^ ((r16 >> 1) & 3)) << 3);

  f32x4 acc[24];
#pragma unroll
  for (int f = 0; f < 24; ++f) acc[f] = (f32x4){0.f, 0.f, 0.f, 0.f};

  // B staging: wave wv stages Wi rows wv*192..+191 (12 chunks of 16 rows).
  // A staging: waves 0,1 stage comp rows wv*16..+15.
  const int arow = wv * 16 + srow;                  // waves 0,1 only
  const u16* gA = compH + (size_t)(bs * 32 + arow) * DD
                + (((slot ^ ((arow >> 1) & 3))) << 3);

  auto stage = [&](int kt, int buf){
    const int k0 = kt << 5;
    u16* Bp = smem + buf * 25600;
#pragma unroll
    for (int it = 0; it < 12; ++it){
      const int n = wv * 192 + it * 16 + srow;
      gload16(WiH + (size_t)n * DD + k0 + ((slot ^ ((n >> 1) & 3)) << 3),
              Bp + (wv * 192 + it * 16) * 32 + lane * 8);
    }
    if (wv < 2)
      gload16(gA + k0, Bp + 24576 + wv * 512 + lane * 8);
  };

  auto compute = [&](int buf){
    u16* Bp = smem + buf * 25600;
    u16* Ap = Bp + 24576;
    const int ar = b * 16 + r16;
    const bf16x8 af = __builtin_bit_cast(bf16x8, *(const int4*)&Ap[ar * 32 + kgsw]);
#pragma unroll
    for (int f = 0; f < 24; ++f){
      const int n = hh * 384 + f * 16 + r16;
      const bf16x8 bf = __builtin_bit_cast(bf16x8, *(const int4*)&Bp[n * 32 + kgsw]);
      acc[f] = __builtin_amdgcn_mfma_f32_16x16x32_bf16(af, bf, acc[f], 0, 0, 0);
    }
  };

  stage(0, 0);
  __syncthreads();
  int cur = 0;
  for (int kt = 0; kt < 24; ++kt){
    if (kt + 1 < 24) stage(kt + 1, cur ^ 1);
    compute(cur);
    __syncthreads();
    cur ^= 1;
  }

  // ---- epilogue: gelu + residual, LN stats, energy, softmax, span ----------
  float* st = (float*)smem;   // staging LDS is dead now (barrier above)
  const size_t rowb = (size_t)(bs * 32 + b * 16 + kg * 4) * DD;
#pragma unroll
  for (int f = 0; f < 24; ++f){
    const int col = hh * 384 + f * 16 + r16;
    const float bias = ib[col];
#pragma unroll
    for (int r = 0; r < 4; ++r){
      const size_t idx = rowb + (size_t)r * DD + col;
      const float cv = bf2f(compH[idx]) + bf2f(compL[idx]);
      acc[f][r] = gelu_f(acc[f][r] + bias) + cv;
    }
  }
  // row sums / sumsq
  float s0[4] = {0.f,0.f,0.f,0.f}, q0[4] = {0.f,0.f,0.f,0.f};
#pragma unroll
  for (int f = 0; f < 24; ++f)
#pragma unroll
    for (int r = 0; r < 4; ++r){ const float v = acc[f][r]; s0[r] += v; q0[r] += v * v; }
#pragma unroll
  for (int off = 1; off < 16; off <<= 1)
#pragma unroll
    for (int r = 0; r < 4; ++r){ s0[r] += __shfl_xor(s0[r], off, 64); q0[r] += __shfl_xor(q0[r], off, 64); }
  if (r16 == 0){
    const int row = b * 16 + kg * 4;
#pragma unroll
    for (int r = 0; r < 4; ++r){
      st[(row + r) * 2 + hh] = s0[r];
      st[64 + (row + r) * 2 + hh] = q0[r];
    }
  }
  __syncthreads();
  if (t < 32){
    const float sum = st[t * 2] + st[t * 2 + 1];
    const float sq  = st[64 + t * 2] + st[64 + t * 2 + 1];
    const float mu = sum * (1.f / 768.f);
    const float var = sq * (1.f / 768.f) - mu * mu;
    st[128 + t] = mu;
    st[160 + t] = rsqrtf(var + 1e-12f);
  }
  __syncthreads();
  float mur[4], rsr[4];
#pragma unroll
  for (int r = 0; r < 4; ++r){
    mur[r] = st[128 + b * 16 + kg * 4 + r];
    rsr[r] = st[160 + b * 16 + kg * 4 + r];
  }
  // energy partials
  float e0[4] = {0.f,0.f,0.f,0.f};
#pragma unroll
  for (int f = 0; f < 24; ++f){
    const int col = hh * 384 + f * 16 + r16;
    const float gc = g[col], bc = lnb[col], wc = ew[col];
#pragma unroll
    for (int r = 0; r < 4; ++r)
      e0[r] += ((acc[f][r] - mur[r]) * rsr[r] * gc + bc) * wc;
  }
#pragma unroll
  for (int off = 1; off < 16; off <<= 1)
#pragma unroll
    for (int r = 0; r < 4; ++r) e0[r] += __shfl_xor(e0[r], off, 64);
  if (r16 == 0){
    const int row = b * 16 + kg * 4;
#pragma unroll
    for (int r = 0; r < 4; ++r) st[192 + (row + r) * 2 + hh] = e0[r];
  }
  __syncthreads();
  // softmax over 32 rows (energy_b cancels in softmax)
  float mx = -3.4e38f;
#pragma unroll
  for (int n = 0; n < 32; ++n) mx = fmaxf(mx, st[192 + n * 2] + st[192 + n * 2 + 1]);
  float Z = 0.f;
#pragma unroll
  for (int n = 0; n < 32; ++n) Z += expf(st[192 + n * 2] + st[192 + n * 2 + 1] - mx);
  const float ainv = 1.f / Z;
  float ar4[4];
#pragma unroll
  for (int r = 0; r < 4; ++r){
    const int row = b * 16 + kg * 4 + r;
    ar4[r] = expf(st[192 + row * 2] + st[192 + row * 2 + 1] - mx) * ainv;
  }
  // span partials: spl[b][col] at st[256..]
#pragma unroll
  for (int f = 0; f < 24; ++f){
    const int col = hh * 384 + f * 16 + r16;
    const float gc = g[col], bc = lnb[col];
    float v = 0.f;
#pragma unroll
    for (int r = 0; r < 4; ++r)
      v += ar4[r] * ((acc[f][r] - mur[r]) * rsr[r] * gc + bc);
    v += __shfl_xor(v, 16, 64);
    v += __shfl_xor(v, 32, 64);
    if (kg == 0) st[256 + b * 768 + col] = v;
  }
  __syncthreads();
  if (t < 192){
    const float4 v0 = ((const float4*)(st + 256))[t];
    const float4 v1 = ((const float4*)(st + 256 + 768))[t];
    float4 a4;
    a4.x = v0.x + v1.x; a4.y = v0.y + v1.y; a4.z = v0.z + v1.z; a4.w = v0.w + v1.w;
    ((float4*)(span + (size_t)bs * DD))[t] = a4;
    ushort4 h4, l4;
    h4.x = f2bf(a4.x); l4.x = f2bf(a4.x - bf2f(h4.x));
    h4.y = f2bf(a4.y); l4.y = f2bf(a4.y - bf2f(h4.y));
    h4.z = f2bf(a4.z); l4.z = f2bf(a4.z - bf2f(h4.z));
    h4.w = f2bf(a4.w); l4.w = f2bf(a4.w - bf2f(h4.w));
    ((ushort4*)(spanH + (size_t)bs * DD))[t] = h4;
    ((ushort4*)(spanL + (size_t)bs * DD))[t] = l4;
  }
}

// ---------------- weight packing to split bf16 ------------------------------
__global__ __launch_bounds__(256) void k_pack(
    const float* __restrict__ lin_l, const float* __restrict__ lin_r,
    const float* __restrict__ inter_w, const float* __restrict__ ff1,
    const float* __restrict__ ff2, const float* __restrict__ ff4,
    const float* __restrict__ ff3,
    u16* __restrict__ WcH, u16* __restrict__ WcL,
    u16* __restrict__ WiH, u16* __restrict__ WiL,
    u16* __restrict__ Wf1H, u16* __restrict__ Wf1L,
    u16* __restrict__ Wf2H, u16* __restrict__ Wf2L,
    u16* __restrict__ Wf4H, u16* __restrict__ Wf4L,
    u16* __restrict__ Wf3TH, u16* __restrict__ Wf3TL)
{
  const int D2 = DD * DD;
  const int C0 = DD * 1536;
  const int i = blockIdx.x * 256 + threadIdx.x;
  float v; u16 *ph, *pl;
  if (i < C0){
    int d = i / 1536, k = i - d * 1536;
    v = (k < DD) ? lin_l[d * DD + k] : lin_r[d * DD + (k - DD)];
    ph = WcH + i; pl = WcL + i;
  } else if (i < C0 + D2){ int j = i - C0;          v = inter_w[j]; ph = WiH + j;  pl = WiL + j; }
  else if (i < C0 + 2*D2){ int j = i - C0 - D2;     v = ff1[j];     ph = Wf1H + j; pl = Wf1L + j; }
  else if (i < C0 + 3*D2){ int j = i - C0 - 2*D2;   v = ff2[j];     ph = Wf2H + j; pl = Wf2L + j; }
  else if (i < C0 + 4*D2){ int j = i - C0 - 3*D2;   v = ff4[j];     ph = Wf4H + j; pl = Wf4L + j; }
  else if (i < C0 + 5*D2){
    int j = i - C0 - 4*D2; int k = j / DD, d = j - k * DD;
    v = ff3[d * DD + k];  ph = Wf3TH + j; pl = Wf3TL + j;
  } else return;
  const u16 h = f2bf(v);
  *ph = h; *pl = f2bf(v - bf2f(h));
}

// split vis_emb to hi/lo bf16 (512*768 elements) -> rows 0..511 of cmb
__global__ __launch_bounds__(256) void k_vsplit(const float* __restrict__ ve,
    u16* __restrict__ H, u16* __restrict__ L)
{
  const int i = blockIdx.x * 256 + threadIdx.x;
  const float x = ve[i];
  const u16 h = f2bf(x);
  H[i] = h; L[i] = f2bf(x - bf2f(h));
}

// exact f32 GEMVs: sdp[0]=(s0-s1)@ff1^T, sdp[1]=(d0-d1)@ff1^T, sdp[2]=(s1+d1)@ff1^T+b1
__global__ __launch_bounds__(256) void k_smallproj(const float* __restrict__ same_emb,
    const float* __restrict__ den_emb, const float* __restrict__ ff1w,
    const float* __restrict__ ff1b, float* __restrict__ sdp)
{
  __shared__ float xs[DD];
  const int r = blockIdx.x, t = threadIdx.x;
  for (int j = t; j < DD; j += 256){
    float x;
    if (r == 0)      x = same_emb[j] - same_emb[DD + j];
    else if (r == 1) x = den_emb[j] - den_emb[DD + j];
    else             x = same_emb[DD + j] + den_emb[DD + j];
    xs[j] = x;
  }
  __syncthreads();
  for (int j = t; j < DD; j += 256){
    const float* wr = ff1w + (size_t)j * DD;
    float acc = 0.f;
    for (int k = 0; k < DD; ++k) acc += xs[k] * wr[k];
    if (r == 2) acc += ff1b[j];
    sdp[r * DD + j] = acc;
  }
}

__device__ __forceinline__ float block_sum256(float v, volatile float* sm){
#pragma unroll
  for (int off = 32; off; off >>= 1) v += __shfl_down(v, off, 64);
  const int lane = threadIdx.x & 63, wv = threadIdx.x >> 6;
  __syncthreads();
  if (lane == 0) sm[wv] = v;
  __syncthreads();
  return sm[0] + sm[1] + sm[2] + sm[3];
}

// per pair-row: attention dots, 2-way softmax, write w-scaled bf16 A rows.
__global__ __launch_bounds__(256) void k_prep(const float* __restrict__ pt,
    const float* __restrict__ alw, const float* __restrict__ alb,
    const float* __restrict__ arw, const float* __restrict__ arb,
    u16* __restrict__ A1, float* __restrict__ w01)
{
  __shared__ float sm[4];
  const int r = blockIdx.x, t = threadIdx.x;
  const float2* row = (const float2*)(pt + (size_t)r * 1536);
  const float2* alw2 = (const float2*)alw;
  const float2* arw2 = (const float2*)arw;
  float2 x[3]; float wl = 0.f, wr = 0.f;
#pragma unroll
  for (int j = 0; j < 3; ++j){
    const int i2 = t + j * 256;
    x[j] = row[i2];
    if (i2 < 384){ const float2 w = alw2[i2];       wl += x[j].x * w.x + x[j].y * w.y; }
    else         { const float2 w = arw2[i2 - 384]; wr += x[j].x * w.x + x[j].y * w.y; }
  }
  wl = block_sum256(wl, sm);
  wr = block_sum256(wr, sm);
  wl += alb[0]; wr += arb[0];
  const float mx = fmaxf(wl, wr);
  const float e0 = expf(wl - mx), e1 = expf(wr - mx);
  const float inv = 1.f / (e0 + e1);
  const float w0 = e0 * inv, w1 = e1 * inv;
  ushort2* orow = (ushort2*)(A1 + (size_t)r * 1536);
#pragma unroll
  for (int j = 0; j < 3; ++j){
    const int i2 = t + j * 256;
    const float s = (i2 < 384) ? w0 : w1;
    ushort2 o; o.x = f2bf(x[j].x * s); o.y = f2bf(x[j].y * s);
    orow[i2] = o;
  }
  if (t == 0){ w01[2 * r] = w0; w01[2 * r + 1] = w1; }
}

// per (b,s): rm_in = right_vis + span (split)
__global__ __launch_bounds__(256) void k_prep3(const float* __restrict__ vis_emb,
    const float* __restrict__ pairs_den, const float* __restrict__ span,
    u16* __restrict__ rmInH, u16* __restrict__ rmInL)
{
  const int bs = blockIdx.x, t = threadIdx.x;
  const int b = bs >> 7;
  const float* rd = pairs_den + (size_t)bs * 128 + 64;
  const float* ve = vis_emb + (size_t)b * 64 * DD;
  float rv[3] = {0.f, 0.f, 0.f};
  for (int o = 0; o < 64; ++o){
    const float w = rd[o];
#pragma unroll
    for (int j = 0; j < 3; ++j) rv[j] += w * ve[o * DD + t + j * 256];
  }
#pragma unroll
  for (int j = 0; j < 3; ++j){
    const int c = t + j * 256;
    const float v = rv[j] + span[(size_t)bs * DD + c];
    const u16 h = f2bf(v);
    rmInH[(size_t)bs * DD + c] = h;
    rmInL[(size_t)bs * DD + c] = f2bf(v - bf2f(h));
  }
}

// per (b,s): c = dot(ff3_b, right_m)
__global__ __launch_bounds__(64) void k_c(const u16* __restrict__ rmH,
    const u16* __restrict__ rmL, const float* __restrict__ ff3_b,
    float* __restrict__ c)
{
  const int r = blockIdx.x, l = threadIdx.x;
  float s = 0.f;
#pragma unroll
  for (int j = 0; j < 12; ++j){
    const int d = l + j * 64;
    s += (bf2f(rmH[(size_t)r * DD + d]) + bf2f(rmL[(size_t)r * DD + d])) * ff3_b[d];
  }
#pragma unroll
  for (int off = 32; off; off >>= 1) s += __shfl_down(s, off, 64);
  if (l == 0) c[r] = s;
}

// fused final
__global__ __launch_bounds__(256) void k_dot(const float* __restrict__ VE1,
    const float* __restrict__ MQ1, const float* __restrict__ sdp,
    const float* __restrict__ rproj, const float* __restrict__ pairs_den,
    const float* __restrict__ cbuf, const float* __restrict__ obj_mask,
    float* __restrict__ out)
{
  const int bs = blockIdx.x;
  const int b = bs >> 7;
  const int t = threadIdx.x, lane = t & 63, wv = t >> 6;
  float mqc[12], rp[12], d1[12], d2[12];
#pragma unroll
  for (int i = 0; i < 12; ++i){
    const int idx = lane + i * 64;
    mqc[i] = MQ1[(size_t)bs * DD + idx] + sdp[2 * DD + idx];
    rp[i]  = rproj[(size_t)bs * DD + idx];
    d1[i]  = sdp[idx];
    d2[i]  = sdp[DD + idx];
  }
  const float cb = cbuf[bs];
  const float* ldp = pairs_den + (size_t)bs * 128;
  for (int oi = 0; oi < 16; ++oi){
    const int o = wv * 16 + oi;
    const float ld = ldp[o], rd = ldp[64 + o];
    const float* ve = VE1 + ((size_t)(b * 64 + o)) * DD;
    float s = 0.f;
#pragma unroll
    for (int i = 0; i < 12; ++i){
      const float q = ve[lane + i * 64] + mqc[i] + rd * d1[i] + ld * d2[i];
      s += gelu_f(q) * rp[i];
    }
#pragma unroll
    for (int off = 1; off < 64; off <<= 1) s += __shfl_xor(s, off, 64);
    if (lane == 0){
      const float logit = s + cb;
      out[bs * 64 + o] = obj_mask[b * 64 + o] / (1.f + expf(-logit));
    }
  }
}

extern "C" void kernel_launch(void* const* d_in, const int* in_sizes, int n_in,
                              void* d_out, int out_size, void* d_ws, size_t ws_size,
                              hipStream_t stream)
{
  const float* pairs_text = (const float*)d_in[0];
  const float* vis_emb    = (const float*)d_in[1];
  const float* pairs_den  = (const float*)d_in[2];
  const float* obj_mask   = (const float*)d_in[3];
  const float* att_l_w = (const float*)d_in[4];
  const float* att_l_b = (const float*)d_in[5];
  const float* att_r_w = (const float*)d_in[6];
  const float* att_r_b = (const float*)d_in[7];
  const float* lin_l_w = (const float*)d_in[8];
  const float* lin_l_b = (const float*)d_in[9];
  const float* lin_r_w = (const float*)d_in[10];
  const float* lin_r_b = (const float*)d_in[11];
  const float* inter_w = (const float*)d_in[12];
  const float* inter_b = (const float*)d_in[13];
  const float* ln_g = (const float*)d_in[14];
  const float* ln_b = (const float*)d_in[15];
  const float* energy_w = (const float*)d_in[16];
  const float* ff1_w = (const float*)d_in[18];
  const float* ff1_b = (const float*)d_in[19];
  const float* ff2_w = (const float*)d_in[20];
  const float* ff2_b = (const float*)d_in[21];
  const float* ff3_w = (const float*)d_in[22];
  const float* ff3_b = (const float*)d_in[23];
  const float* ff4_w = (const float*)d_in[24];
  const float* ff4_b = (const float*)d_in[25];
  const float* same_emb = (const float*)d_in[26];
  const float* den_emb  = (const float*)d_in[27];

  char* base = (char*)d_ws;
  size_t off = 0;
  auto alloc = [&](size_t bytes) -> void* {
    void* p = base + off;
    off += (bytes + 255) & ~(size_t)255;
    return p;
  };
  // Region A (100.66 MB): A1_hi -> {cmbH,cmbL,OUT,sdp}
  char* RA = (char*)alloc((size_t)R1 * 1536 * 2);
  // Region B (100.66 MB): compH+compL (live G1..k_g2span)
  char* RB = (char*)alloc((size_t)2 * R1 * DD * 2);
  float* w01  = (float*)alloc((size_t)R1 * 2 * 4);
  u16* WcH  = (u16*)alloc((size_t)DD * 1536 * 2);
  u16* WcL  = (u16*)alloc((size_t)DD * 1536 * 2);
  u16* WiH  = (u16*)alloc((size_t)DD * DD * 2);
  u16* WiL  = (u16*)alloc((size_t)DD * DD * 2);
  u16* Wf1H = (u16*)alloc((size_t)DD * DD * 2);
  u16* Wf1L = (u16*)alloc((size_t)DD * DD * 2);
  u16* Wf2H = (u16*)alloc((size_t)DD * DD * 2);
  u16* Wf2L = (u16*)alloc((size_t)DD * DD * 2);
  u16* Wf4H = (u16*)alloc((size_t)DD * DD * 2);
  u16* Wf4L = (u16*)alloc((size_t)DD * DD * 2);
  u16* Wf3TH = (u16*)alloc((size_t)DD * DD * 2);
  u16* Wf3TL = (u16*)alloc((size_t)DD * DD * 2);
  float* span  = (float*)alloc((size_t)NBS * DD * 4);
  u16* rmInH   = (u16*)alloc((size_t)NBS * DD * 2);
  u16* rmInL   = (u16*)alloc((size_t)NBS * DD * 2);
  u16* rm1H    = (u16*)alloc((size_t)NBS * DD * 2);
  u16* rm1L    = (u16*)alloc((size_t)NBS * DD * 2);
  u16* rtMH    = (u16*)alloc((size_t)NBS * DD * 2);
  u16* rtML    = (u16*)alloc((size_t)NBS * DD * 2);
  float* rproj = (float*)alloc((size_t)NBS * DD * 4);
  float* cbuf  = (float*)alloc((size_t)NBS * 4);

  u16*   A1h   = (u16*)RA;            // live: k_prep..G1
  u16*   compH = (u16*)RB;            // live: G1..k_g2span
  u16*   compL = (u16*)(RB + (size_t)R1 * DD * 2);
  // post-G1 aliases inside RA (A1h dead after G1):
  u16*   cmbH  = (u16*)RA;                           // 1536*768*2
  u16*   cmbL  = (u16*)(RA + 2359296);
  float* OUT   = (float*)(RA + 4718592);             // 1536*768*4
  float* sdp   = (float*)(RA + 9437184);             // 3*768*4
  u16*   spanH = cmbH + (size_t)512 * DD;
  u16*   spanL = cmbL + (size_t)512 * DD;
  float* VE1   = OUT;
  float* MQ1   = OUT + (size_t)512 * DD;

  k_pack<<<16128, 256, 0, stream>>>(lin_l_w, lin_r_w, inter_w, ff1_w, ff2_w, ff4_w, ff3_w,
                                    WcH, WcL, WiH, WiL, Wf1H, Wf1L, Wf2H, Wf2L,
                                    Wf4H, Wf4L, Wf3TH, Wf3TL);
  k_prep<<<R1, 256, 0, stream>>>(pairs_text, att_l_w, att_l_b, att_r_w, att_r_b, A1h, w01);
  gemm_bt<EPI_G1, 0, 0><<<6 * (R1 / 128), 256, 0, stream>>>(
      A1h, nullptr, 1536, WcH, nullptr, 1536, compH, compL, nullptr,
      lin_l_b, w01, lin_r_b);
  k_g2span<<<NBS, 256, 0, stream>>>(compH, compL, WiH, inter_b,
                                    ln_g, ln_b, energy_w, span, spanH, spanL);
  k_vsplit<<<512 * DD / 256, 256, 0, stream>>>(vis_emb, cmbH, cmbL);
  k_smallproj<<<3, 256, 0, stream>>>(same_emb, den_emb, ff1_w, ff1_b, sdp);
  k_prep3<<<NBS, 256, 0, stream>>>(vis_emb, pairs_den, span, rmInH, rmInL);
  // merged VE1+MQ1: [vis(512); span(1024)] @ ff1^T, M=1536
  gemm_bt<EPI_F32, 1, 1><<<6 * (1536 / 128), 256, 0, stream>>>(
      cmbH, cmbL, DD, Wf1H, Wf1L, DD, nullptr, nullptr, OUT,
      nullptr, nullptr, nullptr);
  gemm_bt<EPI_GELU_SPLIT, 1, 1><<<6 * (NBS / 128), 256, 0, stream>>>(
      rmInH, rmInL, DD, Wf2H, Wf2L, DD, rm1H, rm1L, nullptr,
      ff2_b, nullptr, nullptr);
  gemm_bt<EPI_BIAS_SPLIT, 1, 1><<<6 * (NBS / 128), 256, 0, stream>>>(
      rm1H, rm1L, DD, Wf4H, Wf4L, DD, rtMH, rtML, nullptr,
      ff4_b, nullptr, nullptr);
  gemm_bt<EPI_F32, 1, 1><<<6 * (NBS / 128), 256, 0, stream>>>(
      rtMH, rtML, DD, Wf3TH, Wf3TL, DD, nullptr, nullptr, rproj,
      nullptr, nullptr, nullptr);
  k_c<<<NBS, 64, 0, stream>>>(rtMH, rtML, ff3_b, cbuf);
  k_dot<<<NBS, 256, 0, stream>>>(VE1, MQ1, sdp, rproj, pairs_den, cbuf, obj_mask,
                                 (float*)d_out);
}

// Round 10
// 663.500 us; speedup vs baseline: 1.2235x; 1.2235x over previous
//
#include <hip/hip_runtime.h>

typedef unsigned short u16;
typedef __bf16 bf16x8 __attribute__((ext_vector_type(8)));
typedef float f32x4 __attribute__((ext_vector_type(4)));

#define R1 32768   // B*S*NS
#define NBS 1024   // B*S
#define DD 768

__device__ __forceinline__ float bf2f(u16 u){
  union { unsigned int u; float f; } v; v.u = ((unsigned int)u) << 16; return v.f;
}
__device__ __forceinline__ u16 f2bf(float f){
  union { float f; unsigned int u; } v; v.f = f;
  unsigned int r = (v.u + 0x7FFFu + ((v.u >> 16) & 1u)) >> 16;
  return (u16)r;
}
__device__ __forceinline__ float gelu_f(float x){
  return 0.5f * x * (1.0f + erff(x * 0.70710678118654752f));
}
__device__ __forceinline__ void gload16(const u16* g, u16* l){
  __builtin_amdgcn_global_load_lds(
      (const __attribute__((address_space(1))) void*)g,
      (__attribute__((address_space(3))) void*)l, 16, 0, 0);
}

enum { EPI_G1 = 0, EPI_GELU_RES = 1, EPI_GELU_SPLIT = 2, EPI_BIAS_SPLIT = 3,
       EPI_F32 = 4 };

// C = A @ Bw^T with split-precision operands. Tile 128x128, BK=32, 4 waves.
// XCD-bijective block swizzle; global_load_lds width-16 staging, LDS writes
// linear with pre-swizzled GLOBAL source cols + XOR-swizzled reads (T2).
// 3-buffer distance-2 pipeline with counted vmcnt (T4).
template<int EPI, int ASPLIT, int WSPLIT>
__global__ __launch_bounds__(256)
void gemm_bt(const u16* __restrict__ Ah, const u16* __restrict__ Al, int lda,
             const u16* __restrict__ Bh, const u16* __restrict__ Bl, int K,
             u16* __restrict__ Ch, u16* __restrict__ Cl, float* __restrict__ Cf,
             const float* __restrict__ bias, const float* __restrict__ w01,
             const float* __restrict__ bias2,
             const u16* __restrict__ resh, const u16* __restrict__ resl)
{
  constexpr int NT = 2 + ASPLIT + WSPLIT;
  constexpr int LPS = NT * 2;                      // stage loads per wave
  __shared__ __align__(16) u16 smem[3 * NT * 4096];

  const int nwg = gridDim.x;            // multiple of 8
  const int xcd = blockIdx.x & 7;
  const int wg = xcd * (nwg >> 3) + (blockIdx.x >> 3);
  const int brow = wg / 6, bcol = wg - brow * 6;
  const int row0 = brow << 7;
  const int col0 = bcol << 7;

  const int t = threadIdx.x;
  const int lane = t & 63;
  const int wv = t >> 6;
  const int wr = (wv >> 1) << 6;
  const int wc = (wv & 1) << 6;
  const int r16 = lane & 15;
  const int kg = lane >> 4;

  f32x4 acc[4][4];
#pragma unroll
  for (int m = 0; m < 4; ++m)
#pragma unroll
    for (int n = 0; n < 4; ++n) acc[m][n] = (f32x4){0.f, 0.f, 0.f, 0.f};

  const int c0 = wv * 2, c1 = c0 + 1;
  const int srow = lane >> 2;
  const int scol = (((lane & 3) ^ ((srow >> 1) & 3)) << 3);
  const u16* gAh0 = Ah + (size_t)(row0 + c0 * 16 + srow) * lda + scol;
  const u16* gAh1 = Ah + (size_t)(row0 + c1 * 16 + srow) * lda + scol;
  const u16* gBh0 = Bh + (size_t)(col0 + c0 * 16 + srow) * K + scol;
  const u16* gBh1 = Bh + (size_t)(col0 + c1 * 16 + srow) * K + scol;
  const u16* gAl0 = ASPLIT ? Al + (size_t)(row0 + c0 * 16 + srow) * lda + scol : nullptr;
  const u16* gAl1 = ASPLIT ? Al + (size_t)(row0 + c1 * 16 + srow) * lda + scol : nullptr;
  const u16* gBl0 = WSPLIT ? Bl + (size_t)(col0 + c0 * 16 + srow) * K + scol : nullptr;
  const u16* gBl1 = WSPLIT ? Bl + (size_t)(col0 + c1 * 16 + srow) * K + scol : nullptr;
  const int o0 = c0 * 512, o1 = c1 * 512;

  auto stage = [&](int kt, int buf){
    const int k0 = kt << 5;
    u16* tb = smem + buf * (NT * 4096);
    u16* AsH = tb;
    u16* BsH = tb + (1 + ASPLIT) * 4096;
    gload16(gAh0 + k0, AsH + o0);
    gload16(gAh1 + k0, AsH + o1);
    gload16(gBh0 + k0, BsH + o0);
    gload16(gBh1 + k0, BsH + o1);
    if constexpr (ASPLIT){
      u16* AsL = tb + 4096;
      gload16(gAl0 + k0, AsL + o0);
      gload16(gAl1 + k0, AsL + o1);
    }
    if constexpr (WSPLIT){
      u16* BsL = tb + (2 + ASPLIT) * 4096;
      gload16(gBl0 + k0, BsL + o0);
      gload16(gBl1 + k0, BsL + o1);
    }
  };

  const int kgsw = ((kg ^ ((r16 >> 1) & 3)) << 3);

  auto compute = [&](int buf){
    u16* tb = smem + buf * (NT * 4096);
    u16* AsH = tb;
    u16* AsL = tb + 4096;
    u16* BsH = tb + (1 + ASPLIT) * 4096;
    u16* BsL = tb + (2 + ASPLIT) * 4096;
    bf16x8 afh[4], bqh[4], afl[4], bql[4];
#pragma unroll
    for (int m = 0; m < 4; ++m)
      afh[m] = __builtin_bit_cast(bf16x8, *(const int4*)&AsH[(wr + m * 16 + r16) * 32 + kgsw]);
#pragma unroll
    for (int n = 0; n < 4; ++n)
      bqh[n] = __builtin_bit_cast(bf16x8, *(const int4*)&BsH[(wc + n * 16 + r16) * 32 + kgsw]);
    if constexpr (ASPLIT)
#pragma unroll
      for (int m = 0; m < 4; ++m)
        afl[m] = __builtin_bit_cast(bf16x8, *(const int4*)&AsL[(wr + m * 16 + r16) * 32 + kgsw]);
    if constexpr (WSPLIT)
#pragma unroll
      for (int n = 0; n < 4; ++n)
        bql[n] = __builtin_bit_cast(bf16x8, *(const int4*)&BsL[(wc + n * 16 + r16) * 32 + kgsw]);
#pragma unroll
    for (int m = 0; m < 4; ++m)
#pragma unroll
      for (int n = 0; n < 4; ++n){
        acc[m][n] = __builtin_amdgcn_mfma_f32_16x16x32_bf16(afh[m], bqh[n], acc[m][n], 0, 0, 0);
        if constexpr (WSPLIT)
          acc[m][n] = __builtin_amdgcn_mfma_f32_16x16x32_bf16(afh[m], bql[n], acc[m][n], 0, 0, 0);
        if constexpr (ASPLIT)
          acc[m][n] = __builtin_amdgcn_mfma_f32_16x16x32_bf16(afl[m], bqh[n], acc[m][n], 0, 0, 0);
      }
  };

  const int nkt = K >> 5;
  stage(0, 0);
  stage(1, 1);
  int cur = 0;
  for (int kt = 0; kt < nkt - 1; ++kt){
    asm volatile("s_waitcnt vmcnt(%0) lgkmcnt(0)" :: "i"(LPS) : "memory");
    __builtin_amdgcn_s_barrier();
    asm volatile("" ::: "memory");
    const int nx = (cur == 0) ? 2 : cur - 1;   // (cur+2)%3
    if (kt + 2 < nkt) stage(kt + 2, nx);
    compute(cur);
    cur = (cur == 2) ? 0 : cur + 1;
  }
  asm volatile("s_waitcnt vmcnt(0) lgkmcnt(0)" ::: "memory");
  __builtin_amdgcn_s_barrier();
  asm volatile("" ::: "memory");
  compute(cur);

#pragma unroll
  for (int m = 0; m < 4; ++m){
#pragma unroll
    for (int r = 0; r < 4; ++r){
      const int row = row0 + wr + m * 16 + kg * 4 + r;
      float rw0 = 0.f, rw1 = 0.f;
      if (EPI == EPI_G1){ rw0 = w01[2 * row]; rw1 = w01[2 * row + 1]; }
#pragma unroll
      for (int n = 0; n < 4; ++n){
        const int col = col0 + wc + n * 16 + r16;
        const size_t idx = (size_t)row * DD + col;
        float v = acc[m][n][r];
        if (EPI == EPI_G1){
          v += rw0 * bias[col] + rw1 * bias2[col];
          const u16 h = f2bf(v);
          Ch[idx] = h; Cl[idx] = f2bf(v - bf2f(h));
        } else if (EPI == EPI_GELU_RES){
          v = gelu_f(v + bias[col]) + bf2f(resh[idx]) + bf2f(resl[idx]);
          Ch[idx] = f2bf(v);                      // tbuf now bf16
        } else if (EPI == EPI_GELU_SPLIT){
          v = gelu_f(v + bias[col]);
          const u16 h = f2bf(v);
          Ch[idx] = h; Cl[idx] = f2bf(v - bf2f(h));
        } else if (EPI == EPI_BIAS_SPLIT){
          v = v + bias[col];
          const u16 h = f2bf(v);
          Ch[idx] = h; Cl[idx] = f2bf(v - bf2f(h));
        } else { // EPI_F32
          Cf[idx] = v;
        }
      }
    }
  }
}

// ---------------- weight packing to split bf16 ------------------------------
__global__ __launch_bounds__(256) void k_pack(
    const float* __restrict__ lin_l, const float* __restrict__ lin_r,
    const float* __restrict__ inter_w, const float* __restrict__ ff1,
    const float* __restrict__ ff2, const float* __restrict__ ff4,
    const float* __restrict__ ff3,
    u16* __restrict__ WcH, u16* __restrict__ WcL,
    u16* __restrict__ WiH, u16* __restrict__ WiL,
    u16* __restrict__ Wf1H, u16* __restrict__ Wf1L,
    u16* __restrict__ Wf2H, u16* __restrict__ Wf2L,
    u16* __restrict__ Wf4H, u16* __restrict__ Wf4L,
    u16* __restrict__ Wf3TH, u16* __restrict__ Wf3TL)
{
  const int D2 = DD * DD;
  const int C0 = DD * 1536;
  const int i = blockIdx.x * 256 + threadIdx.x;
  float v; u16 *ph, *pl;
  if (i < C0){
    int d = i / 1536, k = i - d * 1536;
    v = (k < DD) ? lin_l[d * DD + k] : lin_r[d * DD + (k - DD)];
    ph = WcH + i; pl = WcL + i;
  } else if (i < C0 + D2){ int j = i - C0;          v = inter_w[j]; ph = WiH + j;  pl = WiL + j; }
  else if (i < C0 + 2*D2){ int j = i - C0 - D2;     v = ff1[j];     ph = Wf1H + j; pl = Wf1L + j; }
  else if (i < C0 + 3*D2){ int j = i - C0 - 2*D2;   v = ff2[j];     ph = Wf2H + j; pl = Wf2L + j; }
  else if (i < C0 + 4*D2){ int j = i - C0 - 3*D2;   v = ff4[j];     ph = Wf4H + j; pl = Wf4L + j; }
  else if (i < C0 + 5*D2){
    int j = i - C0 - 4*D2; int k = j / DD, d = j - k * DD;
    v = ff3[d * DD + k];  ph = Wf3TH + j; pl = Wf3TL + j;
  } else return;
  const u16 h = f2bf(v);
  *ph = h; *pl = f2bf(v - bf2f(h));
}

// split vis_emb to hi/lo bf16 (512*768 elements) -> rows 0..511 of cmb
__global__ __launch_bounds__(256) void k_vsplit(const float* __restrict__ ve,
    u16* __restrict__ H, u16* __restrict__ L)
{
  const int i = blockIdx.x * 256 + threadIdx.x;
  const float x = ve[i];
  const u16 h = f2bf(x);
  H[i] = h; L[i] = f2bf(x - bf2f(h));
}

// exact f32 GEMVs: sdp[0]=(s0-s1)@ff1^T, sdp[1]=(d0-d1)@ff1^T, sdp[2]=(s1+d1)@ff1^T+b1
__global__ __launch_bounds__(256) void k_smallproj(const float* __restrict__ same_emb,
    const float* __restrict__ den_emb, const float* __restrict__ ff1w,
    const float* __restrict__ ff1b, float* __restrict__ sdp)
{
  __shared__ float xs[DD];
  const int r = blockIdx.x, t = threadIdx.x;
  for (int j = t; j < DD; j += 256){
    float x;
    if (r == 0)      x = same_emb[j] - same_emb[DD + j];
    else if (r == 1) x = den_emb[j] - den_emb[DD + j];
    else             x = same_emb[DD + j] + den_emb[DD + j];
    xs[j] = x;
  }
  __syncthreads();
  for (int j = t; j < DD; j += 256){
    const float* wr = ff1w + (size_t)j * DD;
    float acc = 0.f;
    for (int k = 0; k < DD; ++k) acc += xs[k] * wr[k];
    if (r == 2) acc += ff1b[j];
    sdp[r * DD + j] = acc;
  }
}

__device__ __forceinline__ float block_sum256(float v, volatile float* sm){
#pragma unroll
  for (int off = 32; off; off >>= 1) v += __shfl_down(v, off, 64);
  const int lane = threadIdx.x & 63, wv = threadIdx.x >> 6;
  __syncthreads();
  if (lane == 0) sm[wv] = v;
  __syncthreads();
  return sm[0] + sm[1] + sm[2] + sm[3];
}

// per pair-row: attention dots, 2-way softmax, write w-scaled bf16 A rows.
__global__ __launch_bounds__(256) void k_prep(const float* __restrict__ pt,
    const float* __restrict__ alw, const float* __restrict__ alb,
    const float* __restrict__ arw, const float* __restrict__ arb,
    u16* __restrict__ A1, float* __restrict__ w01)
{
  __shared__ float sm[4];
  const int r = blockIdx.x, t = threadIdx.x;
  const float2* row = (const float2*)(pt + (size_t)r * 1536);
  const float2* alw2 = (const float2*)alw;
  const float2* arw2 = (const float2*)arw;
  float2 x[3]; float wl = 0.f, wr = 0.f;
#pragma unroll
  for (int j = 0; j < 3; ++j){
    const int i2 = t + j * 256;
    x[j] = row[i2];
    if (i2 < 384){ const float2 w = alw2[i2];       wl += x[j].x * w.x + x[j].y * w.y; }
    else         { const float2 w = arw2[i2 - 384]; wr += x[j].x * w.x + x[j].y * w.y; }
  }
  wl = block_sum256(wl, sm);
  wr = block_sum256(wr, sm);
  wl += alb[0]; wr += arb[0];
  const float mx = fmaxf(wl, wr);
  const float e0 = expf(wl - mx), e1 = expf(wr - mx);
  const float inv = 1.f / (e0 + e1);
  const float w0 = e0 * inv, w1 = e1 * inv;
  ushort2* orow = (ushort2*)(A1 + (size_t)r * 1536);
#pragma unroll
  for (int j = 0; j < 3; ++j){
    const int i2 = t + j * 256;
    const float s = (i2 < 384) ? w0 : w1;
    ushort2 o; o.x = f2bf(x[j].x * s); o.y = f2bf(x[j].y * s);
    orow[i2] = o;
  }
  if (t == 0){ w01[2 * r] = w0; w01[2 * r + 1] = w1; }
}

// fused per-(b,s): LN of 32 rows + energy dots + softmax + span, tbuf bf16.
__global__ __launch_bounds__(256) void k_lnspan(const u16* __restrict__ tbuf,
    const float* __restrict__ g, const float* __restrict__ bb,
    const float* __restrict__ ew, float* __restrict__ span,
    u16* __restrict__ spanH, u16* __restrict__ spanL)
{
  __shared__ float smu[32], srs[32], se[32];
  const int bs = blockIdx.x, t = threadIdx.x;
  const int lane = t & 63, wv = t >> 6;
  const u16* xb = tbuf + (size_t)bs * 32 * DD;
  const float4* g4 = (const float4*)g;
  const float4* b4 = (const float4*)bb;
  const float4* e4 = (const float4*)ew;
  for (int r = wv * 8; r < wv * 8 + 8; ++r){
    const ushort4* xr4 = (const ushort4*)(xb + (size_t)r * DD);
    float4 x4[3]; float s = 0.f, q = 0.f;
#pragma unroll
    for (int j = 0; j < 3; ++j){
      const ushort4 u = xr4[lane * 3 + j];
      float4 v; v.x = bf2f(u.x); v.y = bf2f(u.y); v.z = bf2f(u.z); v.w = bf2f(u.w);
      x4[j] = v;
      s += v.x + v.y + v.z + v.w;
      q += v.x * v.x + v.y * v.y + v.z * v.z + v.w * v.w;
    }
#pragma unroll
    for (int off = 1; off < 64; off <<= 1){ s += __shfl_xor(s, off, 64); q += __shfl_xor(q, off, 64); }
    const float mu = s * (1.f / 768.f);
    const float var = q * (1.f / 768.f) - mu * mu;
    const float rs = rsqrtf(var + 1e-12f);
    float e = 0.f;
#pragma unroll
    for (int j = 0; j < 3; ++j){
      const float4 gv = g4[lane * 3 + j], bv = b4[lane * 3 + j], wv4 = e4[lane * 3 + j];
      e += ((x4[j].x - mu) * rs * gv.x + bv.x) * wv4.x
         + ((x4[j].y - mu) * rs * gv.y + bv.y) * wv4.y
         + ((x4[j].z - mu) * rs * gv.z + bv.z) * wv4.z
         + ((x4[j].w - mu) * rs * gv.w + bv.w) * wv4.w;
    }
#pragma unroll
    for (int off = 1; off < 64; off <<= 1) e += __shfl_xor(e, off, 64);
    if (lane == 0){ smu[r] = mu; srs[r] = rs; se[r] = e; }
  }
  __syncthreads();
  float mx = -3.4e38f;
#pragma unroll
  for (int n = 0; n < 32; ++n) mx = fmaxf(mx, se[n]);
  float a[32]; float Z = 0.f;
#pragma unroll
  for (int n = 0; n < 32; ++n){ a[n] = expf(se[n] - mx); Z += a[n]; }
  const float inv = 1.f / Z;
  if (t < 192){
    const float4 gv = g4[t], bv = b4[t];
    float4 acc = {0.f, 0.f, 0.f, 0.f};
    for (int n = 0; n < 32; ++n){
      const float an = a[n] * inv, mun = smu[n], rsn = srs[n];
      const ushort4 u = ((const ushort4*)(xb + (size_t)n * DD))[t];
      acc.x += an * ((bf2f(u.x) - mun) * rsn * gv.x + bv.x);
      acc.y += an * ((bf2f(u.y) - mun) * rsn * gv.y + bv.y);
      acc.z += an * ((bf2f(u.z) - mun) * rsn * gv.z + bv.z);
      acc.w += an * ((bf2f(u.w) - mun) * rsn * gv.w + bv.w);
    }
    ((float4*)(span + (size_t)bs * DD))[t] = acc;
    ushort4 h, l;
    h.x = f2bf(acc.x); l.x = f2bf(acc.x - bf2f(h.x));
    h.y = f2bf(acc.y); l.y = f2bf(acc.y - bf2f(h.y));
    h.z = f2bf(acc.z); l.z = f2bf(acc.z - bf2f(h.z));
    h.w = f2bf(acc.w); l.w = f2bf(acc.w - bf2f(h.w));
    ((ushort4*)(spanH + (size_t)bs * DD))[t] = h;
    ((ushort4*)(spanL + (size_t)bs * DD))[t] = l;
  }
}

// per (b,s): rm_in = right_vis + span (split)
__global__ __launch_bounds__(256) void k_prep3(const float* __restrict__ vis_emb,
    const float* __restrict__ pairs_den, const float* __restrict__ span,
    u16* __restrict__ rmInH, u16* __restrict__ rmInL)
{
  const int bs = blockIdx.x, t = threadIdx.x;
  const int b = bs >> 7;
  const float* rd = pairs_den + (size_t)bs * 128 + 64;
  const float* ve = vis_emb + (size_t)b * 64 * DD;
  float rv[3] = {0.f, 0.f, 0.f};
  for (int o = 0; o < 64; ++o){
    const float w = rd[o];
#pragma unroll
    for (int j = 0; j < 3; ++j) rv[j] += w * ve[o * DD + t + j * 256];
  }
#pragma unroll
  for (int j = 0; j < 3; ++j){
    const int c = t + j * 256;
    const float v = rv[j] + span[(size_t)bs * DD + c];
    const u16 h = f2bf(v);
    rmInH[(size_t)bs * DD + c] = h;
    rmInL[(size_t)bs * DD + c] = f2bf(v - bf2f(h));
  }
}

// per (b,s): c = dot(ff3_b, right_m)
__global__ __launch_bounds__(64) void k_c(const u16* __restrict__ rmH,
    const u16* __restrict__ rmL, const float* __restrict__ ff3_b,
    float* __restrict__ c)
{
  const int r = blockIdx.x, l = threadIdx.x;
  float s = 0.f;
#pragma unroll
  for (int j = 0; j < 12; ++j){
    const int d = l + j * 64;
    s += (bf2f(rmH[(size_t)r * DD + d]) + bf2f(rmL[(size_t)r * DD + d])) * ff3_b[d];
  }
#pragma unroll
  for (int off = 32; off; off >>= 1) s += __shfl_down(s, off, 64);
  if (l == 0) c[r] = s;
}

// fused final
__global__ __launch_bounds__(256) void k_dot(const float* __restrict__ VE1,
    const float* __restrict__ MQ1, const float* __restrict__ sdp,
    const float* __restrict__ rproj, const float* __restrict__ pairs_den,
    const float* __restrict__ cbuf, const float* __restrict__ obj_mask,
    float* __restrict__ out)
{
  const int bs = blockIdx.x;
  const int b = bs >> 7;
  const int t = threadIdx.x, lane = t & 63, wv = t >> 6;
  float mqc[12], rp[12], d1[12], d2[12];
#pragma unroll
  for (int i = 0; i < 12; ++i){
    const int idx = lane + i * 64;
    mqc[i] = MQ1[(size_t)bs * DD + idx] + sdp[2 * DD + idx];
    rp[i]  = rproj[(size_t)bs * DD + idx];
    d1[i]  = sdp[idx];
    d2[i]  = sdp[DD + idx];
  }
  const float cb = cbuf[bs];
  const float* ldp = pairs_den + (size_t)bs * 128;
  for (int oi = 0; oi < 16; ++oi){
    const int o = wv * 16 + oi;
    const float ld = ldp[o], rd = ldp[64 + o];
    const float* ve = VE1 + ((size_t)(b * 64 + o)) * DD;
    float s = 0.f;
#pragma unroll
    for (int i = 0; i < 12; ++i){
      const float q = ve[lane + i * 64] + mqc[i] + rd * d1[i] + ld * d2[i];
      s += gelu_f(q) * rp[i];
    }
#pragma unroll
    for (int off = 1; off < 64; off <<= 1) s += __shfl_xor(s, off, 64);
    if (lane == 0){
      const float logit = s + cb;
      out[bs * 64 + o] = obj_mask[b * 64 + o] / (1.f + expf(-logit));
    }
  }
}

extern "C" void kernel_launch(void* const* d_in, const int* in_sizes, int n_in,
                              void* d_out, int out_size, void* d_ws, size_t ws_size,
                              hipStream_t stream)
{
  const float* pairs_text = (const float*)d_in[0];
  const float* vis_emb    = (const float*)d_in[1];
  const float* pairs_den  = (const float*)d_in[2];
  const float* obj_mask   = (const float*)d_in[3];
  const float* att_l_w = (const float*)d_in[4];
  const float* att_l_b = (const float*)d_in[5];
  const float* att_r_w = (const float*)d_in[6];
  const float* att_r_b = (const float*)d_in[7];
  const float* lin_l_w = (const float*)d_in[8];
  const float* lin_l_b = (const float*)d_in[9];
  const float* lin_r_w = (const float*)d_in[10];
  const float* lin_r_b = (const float*)d_in[11];
  const float* inter_w = (const float*)d_in[12];
  const float* inter_b = (const float*)d_in[13];
  const float* ln_g = (const float*)d_in[14];
  const float* ln_b = (const float*)d_in[15];
  const float* energy_w = (const float*)d_in[16];
  const float* ff1_w = (const float*)d_in[18];
  const float* ff1_b = (const float*)d_in[19];
  const float* ff2_w = (const float*)d_in[20];
  const float* ff2_b = (const float*)d_in[21];
  const float* ff3_w = (const float*)d_in[22];
  const float* ff3_b = (const float*)d_in[23];
  const float* ff4_w = (const float*)d_in[24];
  const float* ff4_b = (const float*)d_in[25];
  const float* same_emb = (const float*)d_in[26];
  const float* den_emb  = (const float*)d_in[27];

  char* base = (char*)d_ws;
  size_t off = 0;
  auto alloc = [&](size_t bytes) -> void* {
    void* p = base + off;
    off += (bytes + 255) & ~(size_t)255;
    return p;
  };
  // Region A (100.66 MB): A1_hi -> tbuf(bf16, 50MB)
  char* RA = (char*)alloc((size_t)R1 * 1536 * 2);
  // Region B (100.66 MB): compH+compL -> {cmbH,cmbL,OUT,sdp}
  char* RB = (char*)alloc((size_t)2 * R1 * DD * 2);
  float* w01  = (float*)alloc((size_t)R1 * 2 * 4);
  u16* WcH  = (u16*)alloc((size_t)DD * 1536 * 2);
  u16* WcL  = (u16*)alloc((size_t)DD * 1536 * 2);
  u16* WiH  = (u16*)alloc((size_t)DD * DD * 2);
  u16* WiL  = (u16*)alloc((size_t)DD * DD * 2);
  u16* Wf1H = (u16*)alloc((size_t)DD * DD * 2);
  u16* Wf1L = (u16*)alloc((size_t)DD * DD * 2);
  u16* Wf2H = (u16*)alloc((size_t)DD * DD * 2);
  u16* Wf2L = (u16*)alloc((size_t)DD * DD * 2);
  u16* Wf4H = (u16*)alloc((size_t)DD * DD * 2);
  u16* Wf4L = (u16*)alloc((size_t)DD * DD * 2);
  u16* Wf3TH = (u16*)alloc((size_t)DD * DD * 2);
  u16* Wf3TL = (u16*)alloc((size_t)DD * DD * 2);
  float* span  = (float*)alloc((size_t)NBS * DD * 4);
  u16* rmInH   = (u16*)alloc((size_t)NBS * DD * 2);
  u16* rmInL   = (u16*)alloc((size_t)NBS * DD * 2);
  u16* rm1H    = (u16*)alloc((size_t)NBS * DD * 2);
  u16* rm1L    = (u16*)alloc((size_t)NBS * DD * 2);
  u16* rtMH    = (u16*)alloc((size_t)NBS * DD * 2);
  u16* rtML    = (u16*)alloc((size_t)NBS * DD * 2);
  float* rproj = (float*)alloc((size_t)NBS * DD * 4);
  float* cbuf  = (float*)alloc((size_t)NBS * 4);

  u16*   A1h   = (u16*)RA;            // live: k_prep..G1
  u16*   tbuf  = (u16*)RA;            // live: G2..k_lnspan (bf16, 50MB)
  u16*   compH = (u16*)RB;            // live: G1..G2
  u16*   compL = (u16*)(RB + (size_t)R1 * DD * 2);
  // post-G2 aliases inside RB (compH/compL dead after G2):
  u16*   cmbH  = (u16*)RB;                           // 1536*768*2
  u16*   cmbL  = (u16*)(RB + 2359296);
  float* OUT   = (float*)(RB + 4718592);             // 1536*768*4
  float* sdp   = (float*)(RB + 9437184);             // 3*768*4
  u16*   spanH = cmbH + (size_t)512 * DD;
  u16*   spanL = cmbL + (size_t)512 * DD;
  float* VE1   = OUT;
  float* MQ1   = OUT + (size_t)512 * DD;

  k_pack<<<16128, 256, 0, stream>>>(lin_l_w, lin_r_w, inter_w, ff1_w, ff2_w, ff4_w, ff3_w,
                                    WcH, WcL, WiH, WiL, Wf1H, Wf1L, Wf2H, Wf2L,
                                    Wf4H, Wf4L, Wf3TH, Wf3TL);
  k_prep<<<R1, 256, 0, stream>>>(pairs_text, att_l_w, att_l_b, att_r_w, att_r_b, A1h, w01);
  gemm_bt<EPI_G1, 0, 0><<<6 * (R1 / 128), 256, 0, stream>>>(
      A1h, nullptr, 1536, WcH, nullptr, 1536, compH, compL, nullptr,
      lin_l_b, w01, lin_r_b, nullptr, nullptr);
  gemm_bt<EPI_GELU_RES, 0, 0><<<6 * (R1 / 128), 256, 0, stream>>>(
      compH, nullptr, DD, WiH, nullptr, DD, tbuf, nullptr, nullptr,
      inter_b, nullptr, nullptr, compH, compL);
  k_lnspan<<<NBS, 256, 0, stream>>>(tbuf, ln_g, ln_b, energy_w, span, spanH, spanL);
  k_vsplit<<<512 * DD / 256, 256, 0, stream>>>(vis_emb, cmbH, cmbL);
  k_smallproj<<<3, 256, 0, stream>>>(same_emb, den_emb, ff1_w, ff1_b, sdp);
  k_prep3<<<NBS, 256, 0, stream>>>(vis_emb, pairs_den, span, rmInH, rmInL);
  // merged VE1+MQ1: [vis(512); span(1024)] @ ff1^T, M=1536
  gemm_bt<EPI_F32, 1, 1><<<6 * (1536 / 128), 256, 0, stream>>>(
      cmbH, cmbL, DD, Wf1H, Wf1L, DD, nullptr, nullptr, OUT,
      nullptr, nullptr, nullptr, nullptr, nullptr);
  gemm_bt<EPI_GELU_SPLIT, 1, 1><<<6 * (NBS / 128), 256, 0, stream>>>(
      rmInH, rmInL, DD, Wf2H, Wf2L, DD, rm1H, rm1L, nullptr,
      ff2_b, nullptr, nullptr, nullptr, nullptr);
  gemm_bt<EPI_BIAS_SPLIT, 1, 1><<<6 * (NBS / 128), 256, 0, stream>>>(
      rm1H, rm1L, DD, Wf4H, Wf4L, DD, rtMH, rtML, nullptr,
      ff4_b, nullptr, nullptr, nullptr, nullptr);
  gemm_bt<EPI_F32, 1, 1><<<6 * (NBS / 128), 256, 0, stream>>>(
      rtMH, rtML, DD, Wf3TH, Wf3TL, DD, nullptr, nullptr, rproj,
      nullptr, nullptr, nullptr, nullptr, nullptr);
  k_c<<<NBS, 64, 0, stream>>>(rtMH, rtML, ff3_b, cbuf);
  k_dot<<<NBS, 256, 0, stream>>>(VE1, MQ1, sdp, rproj, pairs_den, cbuf, obj_mask,
                                 (float*)d_out);
}

// Round 11
// 564.550 us; speedup vs baseline: 1.4380x; 1.1753x over previous
//
#include <hip/hip_runtime.h>

typedef unsigned short u16;
typedef __bf16 bf16x8 __attribute__((ext_vector_type(8)));
typedef float f32x4 __attribute__((ext_vector_type(4)));

#define R1 32768   // B*S*NS
#define NBS 1024   // B*S
#define DD 768

__device__ __forceinline__ float bf2f(u16 u){
  union { unsigned int u; float f; } v; v.u = ((unsigned int)u) << 16; return v.f;
}
__device__ __forceinline__ u16 f2bf(float f){
  union { float f; unsigned int u; } v; v.f = f;
  unsigned int r = (v.u + 0x7FFFu + ((v.u >> 16) & 1u)) >> 16;
  return (u16)r;
}
__device__ __forceinline__ float gelu_f(float x){
  return 0.5f * x * (1.0f + erff(x * 0.70710678118654752f));
}
__device__ __forceinline__ void gload16(const u16* g, u16* l){
  __builtin_amdgcn_global_load_lds(
      (const __attribute__((address_space(1))) void*)g,
      (__attribute__((address_space(3))) void*)l, 16, 0, 0);
}

enum { EPI_G1 = 0, EPI_GELU_RES = 1, EPI_GELU_SPLIT = 2, EPI_BIAS_SPLIT = 3,
       EPI_F32 = 4 };

// C = A @ Bw^T with split-precision operands. Tile 128x128, BK=32, 4 waves.
// XCD-bijective block swizzle; global_load_lds width-16 staging, LDS writes
// linear with pre-swizzled GLOBAL source cols + XOR-swizzled reads (T2).
// 3-buffer distance-2 pipeline with counted vmcnt (T4).
template<int EPI, int ASPLIT, int WSPLIT>
__global__ __launch_bounds__(256)
void gemm_bt(const u16* __restrict__ Ah, const u16* __restrict__ Al, int lda,
             const u16* __restrict__ Bh, const u16* __restrict__ Bl, int K,
             u16* __restrict__ Ch, u16* __restrict__ Cl, float* __restrict__ Cf,
             const float* __restrict__ bias, const float* __restrict__ w01,
             const float* __restrict__ bias2,
             const u16* __restrict__ resh)
{
  constexpr int NT = 2 + ASPLIT + WSPLIT;
  constexpr int LPS = NT * 2;                      // stage loads per wave
  __shared__ __align__(16) u16 smem[3 * NT * 4096];

  const int nwg = gridDim.x;            // multiple of 8
  const int xcd = blockIdx.x & 7;
  const int wg = xcd * (nwg >> 3) + (blockIdx.x >> 3);
  const int brow = wg / 6, bcol = wg - brow * 6;
  const int row0 = brow << 7;
  const int col0 = bcol << 7;

  const int t = threadIdx.x;
  const int lane = t & 63;
  const int wv = t >> 6;
  const int wr = (wv >> 1) << 6;
  const int wc = (wv & 1) << 6;
  const int r16 = lane & 15;
  const int kg = lane >> 4;

  f32x4 acc[4][4];
#pragma unroll
  for (int m = 0; m < 4; ++m)
#pragma unroll
    for (int n = 0; n < 4; ++n) acc[m][n] = (f32x4){0.f, 0.f, 0.f, 0.f};

  const int c0 = wv * 2, c1 = c0 + 1;
  const int srow = lane >> 2;
  const int scol = (((lane & 3) ^ ((srow >> 1) & 3)) << 3);
  const u16* gAh0 = Ah + (size_t)(row0 + c0 * 16 + srow) * lda + scol;
  const u16* gAh1 = Ah + (size_t)(row0 + c1 * 16 + srow) * lda + scol;
  const u16* gBh0 = Bh + (size_t)(col0 + c0 * 16 + srow) * K + scol;
  const u16* gBh1 = Bh + (size_t)(col0 + c1 * 16 + srow) * K + scol;
  const u16* gAl0 = ASPLIT ? Al + (size_t)(row0 + c0 * 16 + srow) * lda + scol : nullptr;
  const u16* gAl1 = ASPLIT ? Al + (size_t)(row0 + c1 * 16 + srow) * lda + scol : nullptr;
  const u16* gBl0 = WSPLIT ? Bl + (size_t)(col0 + c0 * 16 + srow) * K + scol : nullptr;
  const u16* gBl1 = WSPLIT ? Bl + (size_t)(col0 + c1 * 16 + srow) * K + scol : nullptr;
  const int o0 = c0 * 512, o1 = c1 * 512;

  auto stage = [&](int kt, int buf){
    const int k0 = kt << 5;
    u16* tb = smem + buf * (NT * 4096);
    u16* AsH = tb;
    u16* BsH = tb + (1 + ASPLIT) * 4096;
    gload16(gAh0 + k0, AsH + o0);
    gload16(gAh1 + k0, AsH + o1);
    gload16(gBh0 + k0, BsH + o0);
    gload16(gBh1 + k0, BsH + o1);
    if constexpr (ASPLIT){
      u16* AsL = tb + 4096;
      gload16(gAl0 + k0, AsL + o0);
      gload16(gAl1 + k0, AsL + o1);
    }
    if constexpr (WSPLIT){
      u16* BsL = tb + (2 + ASPLIT) * 4096;
      gload16(gBl0 + k0, BsL + o0);
      gload16(gBl1 + k0, BsL + o1);
    }
  };

  const int kgsw = ((kg ^ ((r16 >> 1) & 3)) << 3);

  auto compute = [&](int buf){
    u16* tb = smem + buf * (NT * 4096);
    u16* AsH = tb;
    u16* AsL = tb + 4096;
    u16* BsH = tb + (1 + ASPLIT) * 4096;
    u16* BsL = tb + (2 + ASPLIT) * 4096;
    bf16x8 afh[4], bqh[4], afl[4], bql[4];
#pragma unroll
    for (int m = 0; m < 4; ++m)
      afh[m] = __builtin_bit_cast(bf16x8, *(const int4*)&AsH[(wr + m * 16 + r16) * 32 + kgsw]);
#pragma unroll
    for (int n = 0; n < 4; ++n)
      bqh[n] = __builtin_bit_cast(bf16x8, *(const int4*)&BsH[(wc + n * 16 + r16) * 32 + kgsw]);
    if constexpr (ASPLIT)
#pragma unroll
      for (int m = 0; m < 4; ++m)
        afl[m] = __builtin_bit_cast(bf16x8, *(const int4*)&AsL[(wr + m * 16 + r16) * 32 + kgsw]);
    if constexpr (WSPLIT)
#pragma unroll
      for (int n = 0; n < 4; ++n)
        bql[n] = __builtin_bit_cast(bf16x8, *(const int4*)&BsL[(wc + n * 16 + r16) * 32 + kgsw]);
#pragma unroll
    for (int m = 0; m < 4; ++m)
#pragma unroll
      for (int n = 0; n < 4; ++n){
        acc[m][n] = __builtin_amdgcn_mfma_f32_16x16x32_bf16(afh[m], bqh[n], acc[m][n], 0, 0, 0);
        if constexpr (WSPLIT)
          acc[m][n] = __builtin_amdgcn_mfma_f32_16x16x32_bf16(afh[m], bql[n], acc[m][n], 0, 0, 0);
        if constexpr (ASPLIT)
          acc[m][n] = __builtin_amdgcn_mfma_f32_16x16x32_bf16(afl[m], bqh[n], acc[m][n], 0, 0, 0);
      }
  };

  const int nkt = K >> 5;
  stage(0, 0);
  stage(1, 1);
  int cur = 0;
  for (int kt = 0; kt < nkt - 1; ++kt){
    asm volatile("s_waitcnt vmcnt(%0) lgkmcnt(0)" :: "i"(LPS) : "memory");
    __builtin_amdgcn_s_barrier();
    asm volatile("" ::: "memory");
    const int nx = (cur == 0) ? 2 : cur - 1;   // (cur+2)%3
    if (kt + 2 < nkt) stage(kt + 2, nx);
    compute(cur);
    cur = (cur == 2) ? 0 : cur + 1;
  }
  asm volatile("s_waitcnt vmcnt(0) lgkmcnt(0)" ::: "memory");
  __builtin_amdgcn_s_barrier();
  asm volatile("" ::: "memory");
  compute(cur);

#pragma unroll
  for (int m = 0; m < 4; ++m){
#pragma unroll
    for (int r = 0; r < 4; ++r){
      const int row = row0 + wr + m * 16 + kg * 4 + r;
      float rw0 = 0.f, rw1 = 0.f;
      if (EPI == EPI_G1){ rw0 = w01[2 * row]; rw1 = w01[2 * row + 1]; }
#pragma unroll
      for (int n = 0; n < 4; ++n){
        const int col = col0 + wc + n * 16 + r16;
        const size_t idx = (size_t)row * DD + col;
        float v = acc[m][n][r];
        if (EPI == EPI_G1){
          v += rw0 * bias[col] + rw1 * bias2[col];
          Ch[idx] = f2bf(v);                       // single bf16 (compL dropped)
        } else if (EPI == EPI_GELU_RES){
          v = gelu_f(v + bias[col]) + bf2f(resh[idx]);
          Ch[idx] = f2bf(v);                       // tbuf bf16
        } else if (EPI == EPI_GELU_SPLIT){
          v = gelu_f(v + bias[col]);
          const u16 h = f2bf(v);
          Ch[idx] = h; Cl[idx] = f2bf(v - bf2f(h));
        } else if (EPI == EPI_BIAS_SPLIT){
          v = v + bias[col];
          const u16 h = f2bf(v);
          Ch[idx] = h; Cl[idx] = f2bf(v - bf2f(h));
        } else { // EPI_F32
          Cf[idx] = v;
        }
      }
    }
  }
}

// ---------------- weight packing to split bf16 ------------------------------
__global__ __launch_bounds__(256) void k_pack(
    const float* __restrict__ lin_l, const float* __restrict__ lin_r,
    const float* __restrict__ inter_w, const float* __restrict__ ff1,
    const float* __restrict__ ff2, const float* __restrict__ ff4,
    const float* __restrict__ ff3,
    u16* __restrict__ WcH, u16* __restrict__ WcL,
    u16* __restrict__ WiH, u16* __restrict__ WiL,
    u16* __restrict__ Wf1H, u16* __restrict__ Wf1L,
    u16* __restrict__ Wf2H, u16* __restrict__ Wf2L,
    u16* __restrict__ Wf4H, u16* __restrict__ Wf4L,
    u16* __restrict__ Wf3TH, u16* __restrict__ Wf3TL)
{
  const int D2 = DD * DD;
  const int C0 = DD * 1536;
  const int i = blockIdx.x * 256 + threadIdx.x;
  float v; u16 *ph, *pl;
  if (i < C0){
    int d = i / 1536, k = i - d * 1536;
    v = (k < DD) ? lin_l[d * DD + k] : lin_r[d * DD + (k - DD)];
    ph = WcH + i; pl = WcL + i;
  } else if (i < C0 + D2){ int j = i - C0;          v = inter_w[j]; ph = WiH + j;  pl = WiL + j; }
  else if (i < C0 + 2*D2){ int j = i - C0 - D2;     v = ff1[j];     ph = Wf1H + j; pl = Wf1L + j; }
  else if (i < C0 + 3*D2){ int j = i - C0 - 2*D2;   v = ff2[j];     ph = Wf2H + j; pl = Wf2L + j; }
  else if (i < C0 + 4*D2){ int j = i - C0 - 3*D2;   v = ff4[j];     ph = Wf4H + j; pl = Wf4L + j; }
  else if (i < C0 + 5*D2){
    int j = i - C0 - 4*D2; int k = j / DD, d = j - k * DD;
    v = ff3[d * DD + k];  ph = Wf3TH + j; pl = Wf3TL + j;
  } else return;
  const u16 h = f2bf(v);
  *ph = h; *pl = f2bf(v - bf2f(h));
}

// split vis_emb to hi/lo bf16 (512*768 elements) -> rows 0..511 of cmb
__global__ __launch_bounds__(256) void k_vsplit(const float* __restrict__ ve,
    u16* __restrict__ H, u16* __restrict__ L)
{
  const int i = blockIdx.x * 256 + threadIdx.x;
  const float x = ve[i];
  const u16 h = f2bf(x);
  H[i] = h; L[i] = f2bf(x - bf2f(h));
}

// exact f32 GEMVs, one WAVE per output dot (grid 576 = 2304/4):
// sdp[0]=(s0-s1)@ff1^T, sdp[1]=(d0-d1)@ff1^T, sdp[2]=(s1+d1)@ff1^T+b1
__global__ __launch_bounds__(256) void k_smallproj(const float* __restrict__ same_emb,
    const float* __restrict__ den_emb, const float* __restrict__ ff1w,
    const float* __restrict__ ff1b, float* __restrict__ sdp)
{
  const int j = blockIdx.x * 4 + (threadIdx.x >> 6);   // 0..2303
  const int lane = threadIdx.x & 63;
  const int r = j / DD, jj = j - r * DD;
  const float* wr = ff1w + (size_t)jj * DD;
  float s = 0.f;
#pragma unroll
  for (int i = 0; i < 12; ++i){
    const int k = lane + i * 64;
    float x;
    if (r == 0)      x = same_emb[k] - same_emb[DD + k];
    else if (r == 1) x = den_emb[k] - den_emb[DD + k];
    else             x = same_emb[DD + k] + den_emb[DD + k];
    s += x * wr[k];
  }
#pragma unroll
  for (int off = 32; off; off >>= 1) s += __shfl_down(s, off, 64);
  if (lane == 0) sdp[j] = s + ((r == 2) ? ff1b[jj] : 0.f);
}

__device__ __forceinline__ float block_sum256(float v, volatile float* sm){
#pragma unroll
  for (int off = 32; off; off >>= 1) v += __shfl_down(v, off, 64);
  const int lane = threadIdx.x & 63, wv = threadIdx.x >> 6;
  __syncthreads();
  if (lane == 0) sm[wv] = v;
  __syncthreads();
  return sm[0] + sm[1] + sm[2] + sm[3];
}

// per pair-row: attention dots, 2-way softmax, write w-scaled bf16 A rows.
__global__ __launch_bounds__(256) void k_prep(const float* __restrict__ pt,
    const float* __restrict__ alw, const float* __restrict__ alb,
    const float* __restrict__ arw, const float* __restrict__ arb,
    u16* __restrict__ A1, float* __restrict__ w01)
{
  __shared__ float sm[4];
  const int r = blockIdx.x, t = threadIdx.x;
  const float2* row = (const float2*)(pt + (size_t)r * 1536);
  const float2* alw2 = (const float2*)alw;
  const float2* arw2 = (const float2*)arw;
  float2 x[3]; float wl = 0.f, wr = 0.f;
#pragma unroll
  for (int j = 0; j < 3; ++j){
    const int i2 = t + j * 256;
    x[j] = row[i2];
    if (i2 < 384){ const float2 w = alw2[i2];       wl += x[j].x * w.x + x[j].y * w.y; }
    else         { const float2 w = arw2[i2 - 384]; wr += x[j].x * w.x + x[j].y * w.y; }
  }
  wl = block_sum256(wl, sm);
  wr = block_sum256(wr, sm);
  wl += alb[0]; wr += arb[0];
  const float mx = fmaxf(wl, wr);
  const float e0 = expf(wl - mx), e1 = expf(wr - mx);
  const float inv = 1.f / (e0 + e1);
  const float w0 = e0 * inv, w1 = e1 * inv;
  ushort2* orow = (ushort2*)(A1 + (size_t)r * 1536);
#pragma unroll
  for (int j = 0; j < 3; ++j){
    const int i2 = t + j * 256;
    const float s = (i2 < 384) ? w0 : w1;
    ushort2 o; o.x = f2bf(x[j].x * s); o.y = f2bf(x[j].y * s);
    orow[i2] = o;
  }
  if (t == 0){ w01[2 * r] = w0; w01[2 * r + 1] = w1; }
}

// fused per-(b,s): LN of 32 rows + energy dots + softmax + span, tbuf bf16.
__global__ __launch_bounds__(256) void k_lnspan(const u16* __restrict__ tbuf,
    const float* __restrict__ g, const float* __restrict__ bb,
    const float* __restrict__ ew, float* __restrict__ span,
    u16* __restrict__ spanH, u16* __restrict__ spanL)
{
  __shared__ float smu[32], srs[32], se[32];
  const int bs = blockIdx.x, t = threadIdx.x;
  const int lane = t & 63, wv = t >> 6;
  const u16* xb = tbuf + (size_t)bs * 32 * DD;
  const float4* g4 = (const float4*)g;
  const float4* b4 = (const float4*)bb;
  const float4* e4 = (const float4*)ew;
  for (int r = wv * 8; r < wv * 8 + 8; ++r){
    const ushort4* xr4 = (const ushort4*)(xb + (size_t)r * DD);
    float4 x4[3]; float s = 0.f, q = 0.f;
#pragma unroll
    for (int j = 0; j < 3; ++j){
      const ushort4 u = xr4[lane * 3 + j];
      float4 v; v.x = bf2f(u.x); v.y = bf2f(u.y); v.z = bf2f(u.z); v.w = bf2f(u.w);
      x4[j] = v;
      s += v.x + v.y + v.z + v.w;
      q += v.x * v.x + v.y * v.y + v.z * v.z + v.w * v.w;
    }
#pragma unroll
    for (int off = 1; off < 64; off <<= 1){ s += __shfl_xor(s, off, 64); q += __shfl_xor(q, off, 64); }
    const float mu = s * (1.f / 768.f);
    const float var = q * (1.f / 768.f) - mu * mu;
    const float rs = rsqrtf(var + 1e-12f);
    float e = 0.f;
#pragma unroll
    for (int j = 0; j < 3; ++j){
      const float4 gv = g4[lane * 3 + j], bv = b4[lane * 3 + j], wv4 = e4[lane * 3 + j];
      e += ((x4[j].x - mu) * rs * gv.x + bv.x) * wv4.x
         + ((x4[j].y - mu) * rs * gv.y + bv.y) * wv4.y
         + ((x4[j].z - mu) * rs * gv.z + bv.z) * wv4.z
         + ((x4[j].w - mu) * rs * gv.w + bv.w) * wv4.w;
    }
#pragma unroll
    for (int off = 1; off < 64; off <<= 1) e += __shfl_xor(e, off, 64);
    if (lane == 0){ smu[r] = mu; srs[r] = rs; se[r] = e; }
  }
  __syncthreads();
  float mx = -3.4e38f;
#pragma unroll
  for (int n = 0; n < 32; ++n) mx = fmaxf(mx, se[n]);
  float a[32]; float Z = 0.f;
#pragma unroll
  for (int n = 0; n < 32; ++n){ a[n] = expf(se[n] - mx); Z += a[n]; }
  const float inv = 1.f / Z;
  if (t < 192){
    const float4 gv = g4[t], bv = b4[t];
    float4 acc = {0.f, 0.f, 0.f, 0.f};
    for (int n = 0; n < 32; ++n){
      const float an = a[n] * inv, mun = smu[n], rsn = srs[n];
      const ushort4 u = ((const ushort4*)(xb + (size_t)n * DD))[t];
      acc.x += an * ((bf2f(u.x) - mun) * rsn * gv.x + bv.x);
      acc.y += an * ((bf2f(u.y) - mun) * rsn * gv.y + bv.y);
      acc.z += an * ((bf2f(u.z) - mun) * rsn * gv.z + bv.z);
      acc.w += an * ((bf2f(u.w) - mun) * rsn * gv.w + bv.w);
    }
    ((float4*)(span + (size_t)bs * DD))[t] = acc;
    ushort4 h, l;
    h.x = f2bf(acc.x); l.x = f2bf(acc.x - bf2f(h.x));
    h.y = f2bf(acc.y); l.y = f2bf(acc.y - bf2f(h.y));
    h.z = f2bf(acc.z); l.z = f2bf(acc.z - bf2f(h.z));
    h.w = f2bf(acc.w); l.w = f2bf(acc.w - bf2f(h.w));
    ((ushort4*)(spanH + (size_t)bs * DD))[t] = h;
    ((ushort4*)(spanL + (size_t)bs * DD))[t] = l;
  }
}

// per (b,s): rm_in = right_vis + span (split)
__global__ __launch_bounds__(256) void k_prep3(const float* __restrict__ vis_emb,
    const float* __restrict__ pairs_den, const float* __restrict__ span,
    u16* __restrict__ rmInH, u16* __restrict__ rmInL)
{
  const int bs = blockIdx.x, t = threadIdx.x;
  const int b = bs >> 7;
  const float* rd = pairs_den + (size_t)bs * 128 + 64;
  const float* ve = vis_emb + (size_t)b * 64 * DD;
  float rv[3] = {0.f, 0.f, 0.f};
  for (int o = 0; o < 64; ++o){
    const float w = rd[o];
#pragma unroll
    for (int j = 0; j < 3; ++j) rv[j] += w * ve[o * DD + t + j * 256];
  }
#pragma unroll
  for (int j = 0; j < 3; ++j){
    const int c = t + j * 256;
    const float v = rv[j] + span[(size_t)bs * DD + c];
    const u16 h = f2bf(v);
    rmInH[(size_t)bs * DD + c] = h;
    rmInL[(size_t)bs * DD + c] = f2bf(v - bf2f(h));
  }
}

// per (b,s): c = dot(ff3_b, right_m)
__global__ __launch_bounds__(64) void k_c(const u16* __restrict__ rmH,
    const u16* __restrict__ rmL, const float* __restrict__ ff3_b,
    float* __restrict__ c)
{
  const int r = blockIdx.x, l = threadIdx.x;
  float s = 0.f;
#pragma unroll
  for (int j = 0; j < 12; ++j){
    const int d = l + j * 64;
    s += (bf2f(rmH[(size_t)r * DD + d]) + bf2f(rmL[(size_t)r * DD + d])) * ff3_b[d];
  }
#pragma unroll
  for (int off = 32; off; off >>= 1) s += __shfl_down(s, off, 64);
  if (l == 0) c[r] = s;
}

// fused final
__global__ __launch_bounds__(256) void k_dot(const float* __restrict__ VE1,
    const float* __restrict__ MQ1, const float* __restrict__ sdp,
    const float* __restrict__ rproj, const float* __restrict__ pairs_den,
    const float* __restrict__ cbuf, const float* __restrict__ obj_mask,
    float* __restrict__ out)
{
  const int bs = blockIdx.x;
  const int b = bs >> 7;
  const int t = threadIdx.x, lane = t & 63, wv = t >> 6;
  float mqc[12], rp[12], d1[12], d2[12];
#pragma unroll
  for (int i = 0; i < 12; ++i){
    const int idx = lane + i * 64;
    mqc[i] = MQ1[(size_t)bs * DD + idx] + sdp[2 * DD + idx];
    rp[i]  = rproj[(size_t)bs * DD + idx];
    d1[i]  = sdp[idx];
    d2[i]  = sdp[DD + idx];
  }
  const float cb = cbuf[bs];
  const float* ldp = pairs_den + (size_t)bs * 128;
  for (int oi = 0; oi < 16; ++oi){
    const int o = wv * 16 + oi;
    const float ld = ldp[o], rd = ldp[64 + o];
    const float* ve = VE1 + ((size_t)(b * 64 + o)) * DD;
    float s = 0.f;
#pragma unroll
    for (int i = 0; i < 12; ++i){
      const float q = ve[lane + i * 64] + mqc[i] + rd * d1[i] + ld * d2[i];
      s += gelu_f(q) * rp[i];
    }
#pragma unroll
    for (int off = 1; off < 64; off <<= 1) s += __shfl_xor(s, off, 64);
    if (lane == 0){
      const float logit = s + cb;
      out[bs * 64 + o] = obj_mask[b * 64 + o] / (1.f + expf(-logit));
    }
  }
}

extern "C" void kernel_launch(void* const* d_in, const int* in_sizes, int n_in,
                              void* d_out, int out_size, void* d_ws, size_t ws_size,
                              hipStream_t stream)
{
  const float* pairs_text = (const float*)d_in[0];
  const float* vis_emb    = (const float*)d_in[1];
  const float* pairs_den  = (const float*)d_in[2];
  const float* obj_mask   = (const float*)d_in[3];
  const float* att_l_w = (const float*)d_in[4];
  const float* att_l_b = (const float*)d_in[5];
  const float* att_r_w = (const float*)d_in[6];
  const float* att_r_b = (const float*)d_in[7];
  const float* lin_l_w = (const float*)d_in[8];
  const float* lin_l_b = (const float*)d_in[9];
  const float* lin_r_w = (const float*)d_in[10];
  const float* lin_r_b = (const float*)d_in[11];
  const float* inter_w = (const float*)d_in[12];
  const float* inter_b = (const float*)d_in[13];
  const float* ln_g = (const float*)d_in[14];
  const float* ln_b = (const float*)d_in[15];
  const float* energy_w = (const float*)d_in[16];
  const float* ff1_w = (const float*)d_in[18];
  const float* ff1_b = (const float*)d_in[19];
  const float* ff2_w = (const float*)d_in[20];
  const float* ff2_b = (const float*)d_in[21];
  const float* ff3_w = (const float*)d_in[22];
  const float* ff3_b = (const float*)d_in[23];
  const float* ff4_w = (const float*)d_in[24];
  const float* ff4_b = (const float*)d_in[25];
  const float* same_emb = (const float*)d_in[26];
  const float* den_emb  = (const float*)d_in[27];

  char* base = (char*)d_ws;
  size_t off = 0;
  auto alloc = [&](size_t bytes) -> void* {
    void* p = base + off;
    off += (bytes + 255) & ~(size_t)255;
    return p;
  };
  // Region A (100.66 MB): A1_hi -> tbuf(bf16, 50MB)
  char* RA = (char*)alloc((size_t)R1 * 1536 * 2);
  // Region B (50.33 MB + aliases): compH -> {cmbH,cmbL,OUT,sdp}
  char* RB = (char*)alloc((size_t)2 * R1 * DD * 2);
  float* w01  = (float*)alloc((size_t)R1 * 2 * 4);
  u16* WcH  = (u16*)alloc((size_t)DD * 1536 * 2);
  u16* WcL  = (u16*)alloc((size_t)DD * 1536 * 2);
  u16* WiH  = (u16*)alloc((size_t)DD * DD * 2);
  u16* WiL  = (u16*)alloc((size_t)DD * DD * 2);
  u16* Wf1H = (u16*)alloc((size_t)DD * DD * 2);
  u16* Wf1L = (u16*)alloc((size_t)DD * DD * 2);
  u16* Wf2H = (u16*)alloc((size_t)DD * DD * 2);
  u16* Wf2L = (u16*)alloc((size_t)DD * DD * 2);
  u16* Wf4H = (u16*)alloc((size_t)DD * DD * 2);
  u16* Wf4L = (u16*)alloc((size_t)DD * DD * 2);
  u16* Wf3TH = (u16*)alloc((size_t)DD * DD * 2);
  u16* Wf3TL = (u16*)alloc((size_t)DD * DD * 2);
  float* span  = (float*)alloc((size_t)NBS * DD * 4);
  u16* rmInH   = (u16*)alloc((size_t)NBS * DD * 2);
  u16* rmInL   = (u16*)alloc((size_t)NBS * DD * 2);
  u16* rm1H    = (u16*)alloc((size_t)NBS * DD * 2);
  u16* rm1L    = (u16*)alloc((size_t)NBS * DD * 2);
  u16* rtMH    = (u16*)alloc((size_t)NBS * DD * 2);
  u16* rtML    = (u16*)alloc((size_t)NBS * DD * 2);
  float* rproj = (float*)alloc((size_t)NBS * DD * 4);
  float* cbuf  = (float*)alloc((size_t)NBS * 4);

  u16*   A1h   = (u16*)RA;            // live: k_prep..G1
  u16*   tbuf  = (u16*)RA;            // live: G2..k_lnspan (bf16, 50MB)
  u16*   compH = (u16*)RB;            // live: G1..G2 (50MB)
  // post-G2 aliases inside RB (compH dead after G2):
  u16*   cmbH  = (u16*)RB;                           // 1536*768*2
  u16*   cmbL  = (u16*)(RB + 2359296);
  float* OUT   = (float*)(RB + 4718592);             // 1536*768*4
  float* sdp   = (float*)(RB + 9437184);             // 3*768*4
  u16*   spanH = cmbH + (size_t)512 * DD;
  u16*   spanL = cmbL + (size_t)512 * DD;
  float* VE1   = OUT;
  float* MQ1   = OUT + (size_t)512 * DD;

  k_pack<<<16128, 256, 0, stream>>>(lin_l_w, lin_r_w, inter_w, ff1_w, ff2_w, ff4_w, ff3_w,
                                    WcH, WcL, WiH, WiL, Wf1H, Wf1L, Wf2H, Wf2L,
                                    Wf4H, Wf4L, Wf3TH, Wf3TL);
  k_prep<<<R1, 256, 0, stream>>>(pairs_text, att_l_w, att_l_b, att_r_w, att_r_b, A1h, w01);
  gemm_bt<EPI_G1, 0, 0><<<6 * (R1 / 128), 256, 0, stream>>>(
      A1h, nullptr, 1536, WcH, nullptr, 1536, compH, nullptr, nullptr,
      lin_l_b, w01, lin_r_b, nullptr);
  gemm_bt<EPI_GELU_RES, 0, 0><<<6 * (R1 / 128), 256, 0, stream>>>(
      compH, nullptr, DD, WiH, nullptr, DD, tbuf, nullptr, nullptr,
      inter_b, nullptr, nullptr, compH);
  k_lnspan<<<NBS, 256, 0, stream>>>(tbuf, ln_g, ln_b, energy_w, span, spanH, spanL);
  k_vsplit<<<512 * DD / 256, 256, 0, stream>>>(vis_emb, cmbH, cmbL);
  k_smallproj<<<576, 256, 0, stream>>>(same_emb, den_emb, ff1_w, ff1_b, sdp);
  k_prep3<<<NBS, 256, 0, stream>>>(vis_emb, pairs_den, span, rmInH, rmInL);
  // merged VE1+MQ1: [vis(512); span(1024)] @ ff1^T, M=1536
  gemm_bt<EPI_F32, 1, 1><<<6 * (1536 / 128), 256, 0, stream>>>(
      cmbH, cmbL, DD, Wf1H, Wf1L, DD, nullptr, nullptr, OUT,
      nullptr, nullptr, nullptr, nullptr);
  gemm_bt<EPI_GELU_SPLIT, 1, 1><<<6 * (NBS / 128), 256, 0, stream>>>(
      rmInH, rmInL, DD, Wf2H, Wf2L, DD, rm1H, rm1L, nullptr,
      ff2_b, nullptr, nullptr, nullptr);
  gemm_bt<EPI_BIAS_SPLIT, 1, 1><<<6 * (NBS / 128), 256, 0, stream>>>(
      rm1H, rm1L, DD, Wf4H, Wf4L, DD, rtMH, rtML, nullptr,
      ff4_b, nullptr, nullptr, nullptr);
  gemm_bt<EPI_F32, 1, 1><<<6 * (NBS / 128), 256, 0, stream>>>(
      rtMH, rtML, DD, Wf3TH, Wf3TL, DD, nullptr, nullptr, rproj,
      nullptr, nullptr, nullptr, nullptr);
  k_c<<<NBS, 64, 0, stream>>>(rtMH, rtML, ff3_b, cbuf);
  k_dot<<<NBS, 256, 0, stream>>>(VE1, MQ1, sdp, rproj, pairs_den, cbuf, obj_mask,
                                 (float*)d_out);
}

// Round 13
// 555.686 us; speedup vs baseline: 1.4609x; 1.0160x over previous
//
#include <hip/hip_runtime.h>

typedef unsigned short u16;
typedef __bf16 bf16x8 __attribute__((ext_vector_type(8)));
typedef float f32x4 __attribute__((ext_vector_type(4)));

#define R1 32768   // B*S*NS
#define NBS 1024   // B*S
#define DD 768

__device__ __forceinline__ float bf2f(u16 u){
  union { unsigned int u; float f; } v; v.u = ((unsigned int)u) << 16; return v.f;
}
__device__ __forceinline__ u16 f2bf(float f){
  union { float f; unsigned int u; } v; v.f = f;
  unsigned int r = (v.u + 0x7FFFu + ((v.u >> 16) & 1u)) >> 16;
  return (u16)r;
}
__device__ __forceinline__ float gelu_f(float x){
  return 0.5f * x * (1.0f + erff(x * 0.70710678118654752f));
}
__device__ __forceinline__ void gload16(const u16* g, u16* l){
  __builtin_amdgcn_global_load_lds(
      (const __attribute__((address_space(1))) void*)g,
      (__attribute__((address_space(3))) void*)l, 16, 0, 0);
}

enum { EPI_G1 = 0, EPI_GELU_RES = 1, EPI_GELU_SPLIT = 2, EPI_BIAS_SPLIT = 3,
       EPI_F32 = 4 };

// C = A @ Bw^T with split-precision operands. Tile 128x128, BK=32, 4 waves.
// XCD-bijective block swizzle; global_load_lds width-16 staging, LDS writes
// linear with pre-swizzled GLOBAL source cols + XOR-swizzled reads (T2).
// 3-buffer distance-2 pipeline with counted vmcnt (T4).
template<int EPI, int ASPLIT, int WSPLIT>
__global__ __launch_bounds__(256)
void gemm_bt(const u16* __restrict__ Ah, const u16* __restrict__ Al, int lda,
             const u16* __restrict__ Bh, const u16* __restrict__ Bl, int K,
             u16* __restrict__ Ch, u16* __restrict__ Cl, float* __restrict__ Cf,
             const float* __restrict__ bias, const float* __restrict__ w01,
             const float* __restrict__ bias2,
             const u16* __restrict__ resh)
{
  constexpr int NT = 2 + ASPLIT + WSPLIT;
  constexpr int LPS = NT * 2;                      // stage loads per wave
  __shared__ __align__(16) u16 smem[3 * NT * 4096];

  const int nwg = gridDim.x;            // multiple of 8
  const int xcd = blockIdx.x & 7;
  const int wg = xcd * (nwg >> 3) + (blockIdx.x >> 3);
  const int brow = wg / 6, bcol = wg - brow * 6;
  const int row0 = brow << 7;
  const int col0 = bcol << 7;

  const int t = threadIdx.x;
  const int lane = t & 63;
  const int wv = t >> 6;
  const int wr = (wv >> 1) << 6;
  const int wc = (wv & 1) << 6;
  const int r16 = lane & 15;
  const int kg = lane >> 4;

  f32x4 acc[4][4];
#pragma unroll
  for (int m = 0; m < 4; ++m)
#pragma unroll
    for (int n = 0; n < 4; ++n) acc[m][n] = (f32x4){0.f, 0.f, 0.f, 0.f};

  const int c0 = wv * 2, c1 = c0 + 1;
  const int srow = lane >> 2;
  const int scol = (((lane & 3) ^ ((srow >> 1) & 3)) << 3);
  const u16* gAh0 = Ah + (size_t)(row0 + c0 * 16 + srow) * lda + scol;
  const u16* gAh1 = Ah + (size_t)(row0 + c1 * 16 + srow) * lda + scol;
  const u16* gBh0 = Bh + (size_t)(col0 + c0 * 16 + srow) * K + scol;
  const u16* gBh1 = Bh + (size_t)(col0 + c1 * 16 + srow) * K + scol;
  const u16* gAl0 = ASPLIT ? Al + (size_t)(row0 + c0 * 16 + srow) * lda + scol : nullptr;
  const u16* gAl1 = ASPLIT ? Al + (size_t)(row0 + c1 * 16 + srow) * lda + scol : nullptr;
  const u16* gBl0 = WSPLIT ? Bl + (size_t)(col0 + c0 * 16 + srow) * K + scol : nullptr;
  const u16* gBl1 = WSPLIT ? Bl + (size_t)(col0 + c1 * 16 + srow) * K + scol : nullptr;
  const int o0 = c0 * 512, o1 = c1 * 512;

  auto stage = [&](int kt, int buf){
    const int k0 = kt << 5;
    u16* tb = smem + buf * (NT * 4096);
    u16* AsH = tb;
    u16* BsH = tb + (1 + ASPLIT) * 4096;
    gload16(gAh0 + k0, AsH + o0);
    gload16(gAh1 + k0, AsH + o1);
    gload16(gBh0 + k0, BsH + o0);
    gload16(gBh1 + k0, BsH + o1);
    if constexpr (ASPLIT){
      u16* AsL = tb + 4096;
      gload16(gAl0 + k0, AsL + o0);
      gload16(gAl1 + k0, AsL + o1);
    }
    if constexpr (WSPLIT){
      u16* BsL = tb + (2 + ASPLIT) * 4096;
      gload16(gBl0 + k0, BsL + o0);
      gload16(gBl1 + k0, BsL + o1);
    }
  };

  const int kgsw = ((kg ^ ((r16 >> 1) & 3)) << 3);

  auto compute = [&](int buf){
    u16* tb = smem + buf * (NT * 4096);
    u16* AsH = tb;
    u16* AsL = tb + 4096;
    u16* BsH = tb + (1 + ASPLIT) * 4096;
    u16* BsL = tb + (2 + ASPLIT) * 4096;
    bf16x8 afh[4], bqh[4], afl[4], bql[4];
#pragma unroll
    for (int m = 0; m < 4; ++m)
      afh[m] = __builtin_bit_cast(bf16x8, *(const int4*)&AsH[(wr + m * 16 + r16) * 32 + kgsw]);
#pragma unroll
    for (int n = 0; n < 4; ++n)
      bqh[n] = __builtin_bit_cast(bf16x8, *(const int4*)&BsH[(wc + n * 16 + r16) * 32 + kgsw]);
    if constexpr (ASPLIT)
#pragma unroll
      for (int m = 0; m < 4; ++m)
        afl[m] = __builtin_bit_cast(bf16x8, *(const int4*)&AsL[(wr + m * 16 + r16) * 32 + kgsw]);
    if constexpr (WSPLIT)
#pragma unroll
      for (int n = 0; n < 4; ++n)
        bql[n] = __builtin_bit_cast(bf16x8, *(const int4*)&BsL[(wc + n * 16 + r16) * 32 + kgsw]);
#pragma unroll
    for (int m = 0; m < 4; ++m)
#pragma unroll
      for (int n = 0; n < 4; ++n){
        acc[m][n] = __builtin_amdgcn_mfma_f32_16x16x32_bf16(afh[m], bqh[n], acc[m][n], 0, 0, 0);
        if constexpr (WSPLIT)
          acc[m][n] = __builtin_amdgcn_mfma_f32_16x16x32_bf16(afh[m], bql[n], acc[m][n], 0, 0, 0);
        if constexpr (ASPLIT)
          acc[m][n] = __builtin_amdgcn_mfma_f32_16x16x32_bf16(afl[m], bqh[n], acc[m][n], 0, 0, 0);
      }
  };

  const int nkt = K >> 5;
  stage(0, 0);
  stage(1, 1);
  int cur = 0;
  for (int kt = 0; kt < nkt - 1; ++kt){
    asm volatile("s_waitcnt vmcnt(%0) lgkmcnt(0)" :: "i"(LPS) : "memory");
    __builtin_amdgcn_s_barrier();
    asm volatile("" ::: "memory");
    const int nx = (cur == 0) ? 2 : cur - 1;   // (cur+2)%3
    if (kt + 2 < nkt) stage(kt + 2, nx);
    compute(cur);
    cur = (cur == 2) ? 0 : cur + 1;
  }
  asm volatile("s_waitcnt vmcnt(0) lgkmcnt(0)" ::: "memory");
  __builtin_amdgcn_s_barrier();
  asm volatile("" ::: "memory");
  compute(cur);

#pragma unroll
  for (int m = 0; m < 4; ++m){
#pragma unroll
    for (int r = 0; r < 4; ++r){
      const int row = row0 + wr + m * 16 + kg * 4 + r;
      float rw0 = 0.f, rw1 = 0.f;
      if (EPI == EPI_G1){ rw0 = w01[2 * row]; rw1 = w01[2 * row + 1]; }
#pragma unroll
      for (int n = 0; n < 4; ++n){
        const int col = col0 + wc + n * 16 + r16;
        const size_t idx = (size_t)row * DD + col;
        float v = acc[m][n][r];
        if (EPI == EPI_G1){
          v += rw0 * bias[col] + rw1 * bias2[col];
          Ch[idx] = f2bf(v);                       // single bf16 (compL dropped)
        } else if (EPI == EPI_GELU_RES){
          v = gelu_f(v + bias[col]) + bf2f(resh[idx]);
          Ch[idx] = f2bf(v);                       // tbuf bf16
        } else if (EPI == EPI_GELU_SPLIT){
          v = gelu_f(v + bias[col]);
          const u16 h = f2bf(v);
          Ch[idx] = h; Cl[idx] = f2bf(v - bf2f(h));
        } else if (EPI == EPI_BIAS_SPLIT){
          v = v + bias[col];
          const u16 h = f2bf(v);
          Ch[idx] = h; Cl[idx] = f2bf(v - bf2f(h));
        } else { // EPI_F32
          Cf[idx] = v;
        }
      }
    }
  }
}

// ---------------- weight packing to split bf16 ------------------------------
__global__ __launch_bounds__(256) void k_pack(
    const float* __restrict__ lin_l, const float* __restrict__ lin_r,
    const float* __restrict__ inter_w, const float* __restrict__ ff1,
    const float* __restrict__ ff2, const float* __restrict__ ff4,
    const float* __restrict__ ff3,
    u16* __restrict__ WcH, u16* __restrict__ WcL,
    u16* __restrict__ WiH, u16* __restrict__ WiL,
    u16* __restrict__ Wf1H, u16* __restrict__ Wf1L,
    u16* __restrict__ Wf2H, u16* __restrict__ Wf2L,
    u16* __restrict__ Wf4H, u16* __restrict__ Wf4L,
    u16* __restrict__ Wf3TH, u16* __restrict__ Wf3TL)
{
  const int D2 = DD * DD;
  const int C0 = DD * 1536;
  const int i = blockIdx.x * 256 + threadIdx.x;
  float v; u16 *ph, *pl;
  if (i < C0){
    int d = i / 1536, k = i - d * 1536;
    v = (k < DD) ? lin_l[d * DD + k] : lin_r[d * DD + (k - DD)];
    ph = WcH + i; pl = WcL + i;
  } else if (i < C0 + D2){ int j = i - C0;          v = inter_w[j]; ph = WiH + j;  pl = WiL + j; }
  else if (i < C0 + 2*D2){ int j = i - C0 - D2;     v = ff1[j];     ph = Wf1H + j; pl = Wf1L + j; }
  else if (i < C0 + 3*D2){ int j = i - C0 - 2*D2;   v = ff2[j];     ph = Wf2H + j; pl = Wf2L + j; }
  else if (i < C0 + 4*D2){ int j = i - C0 - 3*D2;   v = ff4[j];     ph = Wf4H + j; pl = Wf4L + j; }
  else if (i < C0 + 5*D2){
    int j = i - C0 - 4*D2; int k = j / DD, d = j - k * DD;
    v = ff3[d * DD + k];  ph = Wf3TH + j; pl = Wf3TL + j;
  } else return;
  const u16 h = f2bf(v);
  *ph = h; *pl = f2bf(v - bf2f(h));
}

// split vis_emb to hi/lo bf16 (512*768 elements) -> rows 0..511 of cmb
__global__ __launch_bounds__(256) void k_vsplit(const float* __restrict__ ve,
    u16* __restrict__ H, u16* __restrict__ L)
{
  const int i = blockIdx.x * 256 + threadIdx.x;
  const float x = ve[i];
  const u16 h = f2bf(x);
  H[i] = h; L[i] = f2bf(x - bf2f(h));
}

// exact f32 GEMVs, one WAVE per output dot (grid 576 = 2304/4):
// sdp[0]=(s0-s1)@ff1^T, sdp[1]=(d0-d1)@ff1^T, sdp[2]=(s1+d1)@ff1^T+b1
__global__ __launch_bounds__(256) void k_smallproj(const float* __restrict__ same_emb,
    const float* __restrict__ den_emb, const float* __restrict__ ff1w,
    const float* __restrict__ ff1b, float* __restrict__ sdp)
{
  const int j = blockIdx.x * 4 + (threadIdx.x >> 6);   // 0..2303
  const int lane = threadIdx.x & 63;
  const int r = j / DD, jj = j - r * DD;
  const float* wr = ff1w + (size_t)jj * DD;
  float s = 0.f;
#pragma unroll
  for (int i = 0; i < 12; ++i){
    const int k = lane + i * 64;
    float x;
    if (r == 0)      x = same_emb[k] - same_emb[DD + k];
    else if (r == 1) x = den_emb[k] - den_emb[DD + k];
    else             x = same_emb[DD + k] + den_emb[DD + k];
    s += x * wr[k];
  }
#pragma unroll
  for (int off = 32; off; off >>= 1) s += __shfl_down(s, off, 64);
  if (lane == 0) sdp[j] = s + ((r == 2) ? ff1b[jj] : 0.f);
}

__device__ __forceinline__ float block_sum256(float v, volatile float* sm){
#pragma unroll
  for (int off = 32; off; off >>= 1) v += __shfl_down(v, off, 64);
  const int lane = threadIdx.x & 63, wv = threadIdx.x >> 6;
  __syncthreads();
  if (lane == 0) sm[wv] = v;
  __syncthreads();
  return sm[0] + sm[1] + sm[2] + sm[3];
}

// per pair-row: attention dots, 2-way softmax, write w-scaled bf16 A rows.
// float4 (16B/lane); left/right boundary wave-aligned.
__global__ __launch_bounds__(256) void k_prep(const float* __restrict__ pt,
    const float* __restrict__ alw, const float* __restrict__ alb,
    const float* __restrict__ arw, const float* __restrict__ arb,
    u16* __restrict__ A1, float* __restrict__ w01)
{
  __shared__ float sm[4];
  const int r = blockIdx.x, t = threadIdx.x;
  const float4* row4 = (const float4*)(pt + (size_t)r * 1536);
  const float4* alw4 = (const float4*)alw;
  const float4* arw4 = (const float4*)arw;
  float wl = 0.f, wr = 0.f;
  const float4 x0 = row4[t];                 // f4 idx t: <192 left, else right
  if (t < 192){ const float4 w = alw4[t];
    wl += x0.x * w.x + x0.y * w.y + x0.z * w.z + x0.w * w.w; }
  else        { const float4 w = arw4[t - 192];
    wr += x0.x * w.x + x0.y * w.y + x0.z * w.z + x0.w * w.w; }
  float4 x1 = {0.f, 0.f, 0.f, 0.f};
  if (t < 128){
    x1 = row4[256 + t];                      // f4 idx 256+t: all right
    const float4 w = arw4[64 + t];
    wr += x1.x * w.x + x1.y * w.y + x1.z * w.z + x1.w * w.w;
  }
  wl = block_sum256(wl, sm);
  wr = block_sum256(wr, sm);
  wl += alb[0]; wr += arb[0];
  const float mx = fmaxf(wl, wr);
  const float e0 = expf(wl - mx), e1 = expf(wr - mx);
  const float inv = 1.f / (e0 + e1);
  const float w0 = e0 * inv, w1 = e1 * inv;
  ushort4* orow = (ushort4*)(A1 + (size_t)r * 1536);
  {
    const float s = (t < 192) ? w0 : w1;
    ushort4 o;
    o.x = f2bf(x0.x * s); o.y = f2bf(x0.y * s);
    o.z = f2bf(x0.z * s); o.w = f2bf(x0.w * s);
    orow[t] = o;
  }
  if (t < 128){
    ushort4 o;
    o.x = f2bf(x1.x * w1); o.y = f2bf(x1.y * w1);
    o.z = f2bf(x1.z * w1); o.w = f2bf(x1.w * w1);
    orow[256 + t] = o;
  }
  if (t == 0){ w01[2 * r] = w0; w01[2 * r + 1] = w1; }
}

// fused per-(b,s): LN of 32 rows + energy dots + softmax + span, tbuf bf16.
__global__ __launch_bounds__(256) void k_lnspan(const u16* __restrict__ tbuf,
    const float* __restrict__ g, const float* __restrict__ bb,
    const float* __restrict__ ew, float* __restrict__ span,
    u16* __restrict__ spanH, u16* __restrict__ spanL)
{
  __shared__ float smu[32], srs[32], se[32];
  const int bs = blockIdx.x, t = threadIdx.x;
  const int lane = t & 63, wv = t >> 6;
  const u16* xb = tbuf + (size_t)bs * 32 * DD;
  const float4* g4 = (const float4*)g;
  const float4* b4 = (const float4*)bb;
  const float4* e4 = (const float4*)ew;
  for (int r = wv * 8; r < wv * 8 + 8; ++r){
    const ushort4* xr4 = (const ushort4*)(xb + (size_t)r * DD);
    float4 x4[3]; float s = 0.f, q = 0.f;
#pragma unroll
    for (int j = 0; j < 3; ++j){
      const ushort4 u = xr4[lane * 3 + j];
      float4 v; v.x = bf2f(u.x); v.y = bf2f(u.y); v.z = bf2f(u.z); v.w = bf2f(u.w);
      x4[j] = v;
      s += v.x + v.y + v.z + v.w;
      q += v.x * v.x + v.y * v.y + v.z * v.z + v.w * v.w;
    }
#pragma unroll
    for (int off = 1; off < 64; off <<= 1){ s += __shfl_xor(s, off, 64); q += __shfl_xor(q, off, 64); }
    const float mu = s * (1.f / 768.f);
    const float var = q * (1.f / 768.f) - mu * mu;
    const float rs = rsqrtf(var + 1e-12f);
    float e = 0.f;
#pragma unroll
    for (int j = 0; j < 3; ++j){
      const float4 gv = g4[lane * 3 + j], bv = b4[lane * 3 + j], wv4 = e4[lane * 3 + j];
      e += ((x4[j].x - mu) * rs * gv.x + bv.x) * wv4.x
         + ((x4[j].y - mu) * rs * gv.y + bv.y) * wv4.y
         + ((x4[j].z - mu) * rs * gv.z + bv.z) * wv4.z
         + ((x4[j].w - mu) * rs * gv.w + bv.w) * wv4.w;
    }
#pragma unroll
    for (int off = 1; off < 64; off <<= 1) e += __shfl_xor(e, off, 64);
    if (lane == 0){ smu[r] = mu; srs[r] = rs; se[r] = e; }
  }
  __syncthreads();
  float mx = -3.4e38f;
#pragma unroll
  for (int n = 0; n < 32; ++n) mx = fmaxf(mx, se[n]);
  float a[32]; float Z = 0.f;
#pragma unroll
  for (int n = 0; n < 32; ++n){ a[n] = expf(se[n] - mx); Z += a[n]; }
  const float inv = 1.f / Z;
  if (t < 192){
    const float4 gv = g4[t], bv = b4[t];
    float4 acc = {0.f, 0.f, 0.f, 0.f};
    for (int n = 0; n < 32; ++n){
      const float an = a[n] * inv, mun = smu[n], rsn = srs[n];
      const ushort4 u = ((const ushort4*)(xb + (size_t)n * DD))[t];
      acc.x += an * ((bf2f(u.x) - mun) * rsn * gv.x + bv.x);
      acc.y += an * ((bf2f(u.y) - mun) * rsn * gv.y + bv.y);
      acc.z += an * ((bf2f(u.z) - mun) * rsn * gv.z + bv.z);
      acc.w += an * ((bf2f(u.w) - mun) * rsn * gv.w + bv.w);
    }
    ((float4*)(span + (size_t)bs * DD))[t] = acc;
    ushort4 h, l;
    h.x = f2bf(acc.x); l.x = f2bf(acc.x - bf2f(h.x));
    h.y = f2bf(acc.y); l.y = f2bf(acc.y - bf2f(h.y));
    h.z = f2bf(acc.z); l.z = f2bf(acc.z - bf2f(h.z));
    h.w = f2bf(acc.w); l.w = f2bf(acc.w - bf2f(h.w));
    ((ushort4*)(spanH + (size_t)bs * DD))[t] = h;
    ((ushort4*)(spanL + (size_t)bs * DD))[t] = l;
  }
}

// per (b,s): rm_in = right_vis + span (split)
__global__ __launch_bounds__(256) void k_prep3(const float* __restrict__ vis_emb,
    const float* __restrict__ pairs_den, const float* __restrict__ span,
    u16* __restrict__ rmInH, u16* __restrict__ rmInL)
{
  const int bs = blockIdx.x, t = threadIdx.x;
  const int b = bs >> 7;
  const float* rd = pairs_den + (size_t)bs * 128 + 64;
  const float* ve = vis_emb + (size_t)b * 64 * DD;
  float rv[3] = {0.f, 0.f, 0.f};
  for (int o = 0; o < 64; ++o){
    const float w = rd[o];
#pragma unroll
    for (int j = 0; j < 3; ++j) rv[j] += w * ve[o * DD + t + j * 256];
  }
#pragma unroll
  for (int j = 0; j < 3; ++j){
    const int c = t + j * 256;
    const float v = rv[j] + span[(size_t)bs * DD + c];
    const u16 h = f2bf(v);
    rmInH[(size_t)bs * DD + c] = h;
    rmInL[(size_t)bs * DD + c] = f2bf(v - bf2f(h));
  }
}

// fused final (c-dot inlined as block-wide prologue)
__global__ __launch_bounds__(256) void k_dot(const float* __restrict__ VE1,
    const float* __restrict__ MQ1, const float* __restrict__ sdp,
    const float* __restrict__ rproj, const u16* __restrict__ rtMH,
    const u16* __restrict__ rtML, const float* __restrict__ ff3_b,
    const float* __restrict__ pairs_den, const float* __restrict__ obj_mask,
    float* __restrict__ out)
{
  __shared__ float sm[4];
  const int bs = blockIdx.x;
  const int b = bs >> 7;
  const int t = threadIdx.x, lane = t & 63, wv = t >> 6;
  float cp = 0.f;
#pragma unroll
  for (int j = 0; j < 3; ++j){
    const int d = t + j * 256;
    cp += (bf2f(rtMH[(size_t)bs * DD + d]) + bf2f(rtML[(size_t)bs * DD + d])) * ff3_b[d];
  }
  const float cb = block_sum256(cp, sm);
  float mqc[12], rp[12], d1[12], d2[12];
#pragma unroll
  for (int i = 0; i < 12; ++i){
    const int idx = lane + i * 64;
    mqc[i] = MQ1[(size_t)bs * DD + idx] + sdp[2 * DD + idx];
    rp[i]  = rproj[(size_t)bs * DD + idx];
    d1[i]  = sdp[idx];
    d2[i]  = sdp[DD + idx];
  }
  const float* ldp = pairs_den + (size_t)bs * 128;
  for (int oi = 0; oi < 16; ++oi){
    const int o = wv * 16 + oi;
    const float ld = ldp[o], rd = ldp[64 + o];
    const float* ve = VE1 + ((size_t)(b * 64 + o)) * DD;
    float s = 0.f;
#pragma unroll
    for (int i = 0; i < 12; ++i){
      const float q = ve[lane + i * 64] + mqc[i] + rd * d1[i] + ld * d2[i];
      s += gelu_f(q) * rp[i];
    }
#pragma unroll
    for (int off = 1; off < 64; off <<= 1) s += __shfl_xor(s, off, 64);
    if (lane == 0){
      const float logit = s + cb;
      out[bs * 64 + o] = obj_mask[b * 64 + o] / (1.f + expf(-logit));
    }
  }
}

extern "C" void kernel_launch(void* const* d_in, const int* in_sizes, int n_in,
                              void* d_out, int out_size, void* d_ws, size_t ws_size,
                              hipStream_t stream)
{
  const float* pairs_text = (const float*)d_in[0];
  const float* vis_emb    = (const float*)d_in[1];
  const float* pairs_den  = (const float*)d_in[2];
  const float* obj_mask   = (const float*)d_in[3];
  const float* att_l_w = (const float*)d_in[4];
  const float* att_l_b = (const float*)d_in[5];
  const float* att_r_w = (const float*)d_in[6];
  const float* att_r_b = (const float*)d_in[7];
  const float* lin_l_w = (const float*)d_in[8];
  const float* lin_l_b = (const float*)d_in[9];
  const float* lin_r_w = (const float*)d_in[10];
  const float* lin_r_b = (const float*)d_in[11];
  const float* inter_w = (const float*)d_in[12];
  const float* inter_b = (const float*)d_in[13];
  const float* ln_g = (const float*)d_in[14];
  const float* ln_b = (const float*)d_in[15];
  const float* energy_w = (const float*)d_in[16];
  const float* ff1_w = (const float*)d_in[18];
  const float* ff1_b = (const float*)d_in[19];
  const float* ff2_w = (const float*)d_in[20];
  const float* ff2_b = (const float*)d_in[21];
  const float* ff3_w = (const float*)d_in[22];
  const float* ff3_b = (const float*)d_in[23];
  const float* ff4_w = (const float*)d_in[24];
  const float* ff4_b = (const float*)d_in[25];
  const float* same_emb = (const float*)d_in[26];
  const float* den_emb  = (const float*)d_in[27];

  char* base = (char*)d_ws;
  size_t off = 0;
  auto alloc = [&](size_t bytes) -> void* {
    void* p = base + off;
    off += (bytes + 255) & ~(size_t)255;
    return p;
  };
  // Region A (100.66 MB): A1_hi -> tbuf(bf16, 50MB)
  char* RA = (char*)alloc((size_t)R1 * 1536 * 2);
  // Region B: compH -> {cmbH,cmbL,OUT,sdp}
  char* RB = (char*)alloc((size_t)2 * R1 * DD * 2);
  float* w01  = (float*)alloc((size_t)R1 * 2 * 4);
  u16* WcH  = (u16*)alloc((size_t)DD * 1536 * 2);
  u16* WcL  = (u16*)alloc((size_t)DD * 1536 * 2);
  u16* WiH  = (u16*)alloc((size_t)DD * DD * 2);
  u16* WiL  = (u16*)alloc((size_t)DD * DD * 2);
  u16* Wf1H = (u16*)alloc((size_t)DD * DD * 2);
  u16* Wf1L = (u16*)alloc((size_t)DD * DD * 2);
  u16* Wf2H = (u16*)alloc((size_t)DD * DD * 2);
  u16* Wf2L = (u16*)alloc((size_t)DD * DD * 2);
  u16* Wf4H = (u16*)alloc((size_t)DD * DD * 2);
  u16* Wf4L = (u16*)alloc((size_t)DD * DD * 2);
  u16* Wf3TH = (u16*)alloc((size_t)DD * DD * 2);
  u16* Wf3TL = (u16*)alloc((size_t)DD * DD * 2);
  float* span  = (float*)alloc((size_t)NBS * DD * 4);
  u16* rmInH   = (u16*)alloc((size_t)NBS * DD * 2);
  u16* rmInL   = (u16*)alloc((size_t)NBS * DD * 2);
  u16* rm1H    = (u16*)alloc((size_t)NBS * DD * 2);
  u16* rm1L    = (u16*)alloc((size_t)NBS * DD * 2);
  u16* rtMH    = (u16*)alloc((size_t)NBS * DD * 2);
  u16* rtML    = (u16*)alloc((size_t)NBS * DD * 2);
  float* rproj = (float*)alloc((size_t)NBS * DD * 4);

  u16*   A1h   = (u16*)RA;            // live: k_prep..G1
  u16*   tbuf  = (u16*)RA;            // live: G2..k_lnspan (bf16, 50MB)
  u16*   compH = (u16*)RB;            // live: G1..G2 (50MB)
  // post-G2 aliases inside RB (compH dead after G2):
  u16*   cmbH  = (u16*)RB;                           // 1536*768*2
  u16*   cmbL  = (u16*)(RB + 2359296);
  float* OUT   = (float*)(RB + 4718592);             // 1536*768*4
  float* sdp   = (float*)(RB + 9437184);             // 3*768*4
  u16*   spanH = cmbH + (size_t)512 * DD;
  u16*   spanL = cmbL + (size_t)512 * DD;
  float* VE1   = OUT;
  float* MQ1   = OUT + (size_t)512 * DD;

  k_pack<<<16128, 256, 0, stream>>>(lin_l_w, lin_r_w, inter_w, ff1_w, ff2_w, ff4_w, ff3_w,
                                    WcH, WcL, WiH, WiL, Wf1H, Wf1L, Wf2H, Wf2L,
                                    Wf4H, Wf4L, Wf3TH, Wf3TL);
  k_prep<<<R1, 256, 0, stream>>>(pairs_text, att_l_w, att_l_b, att_r_w, att_r_b, A1h, w01);
  gemm_bt<EPI_G1, 0, 0><<<6 * (R1 / 128), 256, 0, stream>>>(
      A1h, nullptr, 1536, WcH, nullptr, 1536, compH, nullptr, nullptr,
      lin_l_b, w01, lin_r_b, nullptr);
  gemm_bt<EPI_GELU_RES, 0, 0><<<6 * (R1 / 128), 256, 0, stream>>>(
      compH, nullptr, DD, WiH, nullptr, DD, tbuf, nullptr, nullptr,
      inter_b, nullptr, nullptr, compH);
  k_lnspan<<<NBS, 256, 0, stream>>>(tbuf, ln_g, ln_b, energy_w, span, spanH, spanL);
  k_vsplit<<<512 * DD / 256, 256, 0, stream>>>(vis_emb, cmbH, cmbL);
  k_smallproj<<<576, 256, 0, stream>>>(same_emb, den_emb, ff1_w, ff1_b, sdp);
  k_prep3<<<NBS, 256, 0, stream>>>(vis_emb, pairs_den, span, rmInH, rmInL);
  // merged VE1+MQ1: [vis(512); span(1024)] @ ff1^T, M=1536
  gemm_bt<EPI_F32, 1, 1><<<6 * (1536 / 128), 256, 0, stream>>>(
      cmbH, cmbL, DD, Wf1H, Wf1L, DD, nullptr, nullptr, OUT,
      nullptr, nullptr, nullptr, nullptr);
  gemm_bt<EPI_GELU_SPLIT, 1, 1><<<6 * (NBS / 128), 256, 0, stream>>>(
      rmInH, rmInL, DD, Wf2H, Wf2L, DD, rm1H, rm1L, nullptr,
      ff2_b, nullptr, nullptr, nullptr);
  gemm_bt<EPI_BIAS_SPLIT, 1, 1><<<6 * (NBS / 128), 256, 0, stream>>>(
      rm1H, rm1L, DD, Wf4H, Wf4L, DD, rtMH, rtML, nullptr,
      ff4_b, nullptr, nullptr, nullptr);
  gemm_bt<EPI_F32, 1, 1><<<6 * (NBS / 128), 256, 0, stream>>>(
      rtMH, rtML, DD, Wf3TH, Wf3TL, DD, nullptr, nullptr, rproj,
      nullptr, nullptr, nullptr, nullptr);
  k_dot<<<NBS, 256, 0, stream>>>(VE1, MQ1, sdp, rproj, rtMH, rtML, ff3_b,
                                 pairs_den, obj_mask, (float*)d_out);
}

// Round 14
// 546.257 us; speedup vs baseline: 1.4861x; 1.0173x over previous
//
#include <hip/hip_runtime.h>

typedef unsigned short u16;
typedef __bf16 bf16x8 __attribute__((ext_vector_type(8)));
typedef float f32x4 __attribute__((ext_vector_type(4)));

#define R1 32768   // B*S*NS
#define NBS 1024   // B*S
#define DD 768

__device__ __forceinline__ float bf2f(u16 u){
  union { unsigned int u; float f; } v; v.u = ((unsigned int)u) << 16; return v.f;
}
__device__ __forceinline__ u16 f2bf(float f){
  union { float f; unsigned int u; } v; v.f = f;
  unsigned int r = (v.u + 0x7FFFu + ((v.u >> 16) & 1u)) >> 16;
  return (u16)r;
}
__device__ __forceinline__ float gelu_f(float x){
  return 0.5f * x * (1.0f + erff(x * 0.70710678118654752f));
}
__device__ __forceinline__ void gload16(const u16* g, u16* l){
  __builtin_amdgcn_global_load_lds(
      (const __attribute__((address_space(1))) void*)g,
      (__attribute__((address_space(3))) void*)l, 16, 0, 0);
}

enum { EPI_G1 = 0, EPI_GELU_RES = 1, EPI_GELU_SPLIT = 2, EPI_BIAS_SPLIT = 3,
       EPI_F32 = 4 };

// C = A @ Bw^T with split-precision operands. Tile 128x128, BK=32, 4 waves.
// XCD-bijective block swizzle; global_load_lds width-16 staging, LDS writes
// linear with pre-swizzled GLOBAL source cols + XOR-swizzled reads (T2).
// 3-buffer distance-2 pipeline with counted vmcnt (T4).
template<int EPI, int ASPLIT, int WSPLIT>
__global__ __launch_bounds__(256)
void gemm_bt(const u16* __restrict__ Ah, const u16* __restrict__ Al, int lda,
             const u16* __restrict__ Bh, const u16* __restrict__ Bl, int K,
             u16* __restrict__ Ch, u16* __restrict__ Cl, float* __restrict__ Cf,
             const float* __restrict__ bias, const float* __restrict__ w01,
             const float* __restrict__ bias2,
             const u16* __restrict__ resh)
{
  constexpr int NT = 2 + ASPLIT + WSPLIT;
  constexpr int LPS = NT * 2;                      // stage loads per wave
  __shared__ __align__(16) u16 smem[3 * NT * 4096];

  const int nwg = gridDim.x;            // multiple of 8
  const int xcd = blockIdx.x & 7;
  const int wg = xcd * (nwg >> 3) + (blockIdx.x >> 3);
  const int brow = wg / 6, bcol = wg - brow * 6;
  const int row0 = brow << 7;
  const int col0 = bcol << 7;

  const int t = threadIdx.x;
  const int lane = t & 63;
  const int wv = t >> 6;
  const int wr = (wv >> 1) << 6;
  const int wc = (wv & 1) << 6;
  const int r16 = lane & 15;
  const int kg = lane >> 4;

  f32x4 acc[4][4];
#pragma unroll
  for (int m = 0; m < 4; ++m)
#pragma unroll
    for (int n = 0; n < 4; ++n) acc[m][n] = (f32x4){0.f, 0.f, 0.f, 0.f};

  const int c0 = wv * 2, c1 = c0 + 1;
  const int srow = lane >> 2;
  const int scol = (((lane & 3) ^ ((srow >> 1) & 3)) << 3);
  const u16* gAh0 = Ah + (size_t)(row0 + c0 * 16 + srow) * lda + scol;
  const u16* gAh1 = Ah + (size_t)(row0 + c1 * 16 + srow) * lda + scol;
  const u16* gBh0 = Bh + (size_t)(col0 + c0 * 16 + srow) * K + scol;
  const u16* gBh1 = Bh + (size_t)(col0 + c1 * 16 + srow) * K + scol;
  const u16* gAl0 = ASPLIT ? Al + (size_t)(row0 + c0 * 16 + srow) * lda + scol : nullptr;
  const u16* gAl1 = ASPLIT ? Al + (size_t)(row0 + c1 * 16 + srow) * lda + scol : nullptr;
  const u16* gBl0 = WSPLIT ? Bl + (size_t)(col0 + c0 * 16 + srow) * K + scol : nullptr;
  const u16* gBl1 = WSPLIT ? Bl + (size_t)(col0 + c1 * 16 + srow) * K + scol : nullptr;
  const int o0 = c0 * 512, o1 = c1 * 512;

  auto stage = [&](int kt, int buf){
    const int k0 = kt << 5;
    u16* tb = smem + buf * (NT * 4096);
    u16* AsH = tb;
    u16* BsH = tb + (1 + ASPLIT) * 4096;
    gload16(gAh0 + k0, AsH + o0);
    gload16(gAh1 + k0, AsH + o1);
    gload16(gBh0 + k0, BsH + o0);
    gload16(gBh1 + k0, BsH + o1);
    if constexpr (ASPLIT){
      u16* AsL = tb + 4096;
      gload16(gAl0 + k0, AsL + o0);
      gload16(gAl1 + k0, AsL + o1);
    }
    if constexpr (WSPLIT){
      u16* BsL = tb + (2 + ASPLIT) * 4096;
      gload16(gBl0 + k0, BsL + o0);
      gload16(gBl1 + k0, BsL + o1);
    }
  };

  const int kgsw = ((kg ^ ((r16 >> 1) & 3)) << 3);

  auto compute = [&](int buf){
    u16* tb = smem + buf * (NT * 4096);
    u16* AsH = tb;
    u16* AsL = tb + 4096;
    u16* BsH = tb + (1 + ASPLIT) * 4096;
    u16* BsL = tb + (2 + ASPLIT) * 4096;
    bf16x8 afh[4], bqh[4], afl[4], bql[4];
#pragma unroll
    for (int m = 0; m < 4; ++m)
      afh[m] = __builtin_bit_cast(bf16x8, *(const int4*)&AsH[(wr + m * 16 + r16) * 32 + kgsw]);
#pragma unroll
    for (int n = 0; n < 4; ++n)
      bqh[n] = __builtin_bit_cast(bf16x8, *(const int4*)&BsH[(wc + n * 16 + r16) * 32 + kgsw]);
    if constexpr (ASPLIT)
#pragma unroll
      for (int m = 0; m < 4; ++m)
        afl[m] = __builtin_bit_cast(bf16x8, *(const int4*)&AsL[(wr + m * 16 + r16) * 32 + kgsw]);
    if constexpr (WSPLIT)
#pragma unroll
      for (int n = 0; n < 4; ++n)
        bql[n] = __builtin_bit_cast(bf16x8, *(const int4*)&BsL[(wc + n * 16 + r16) * 32 + kgsw]);
#pragma unroll
    for (int m = 0; m < 4; ++m)
#pragma unroll
      for (int n = 0; n < 4; ++n){
        acc[m][n] = __builtin_amdgcn_mfma_f32_16x16x32_bf16(afh[m], bqh[n], acc[m][n], 0, 0, 0);
        if constexpr (WSPLIT)
          acc[m][n] = __builtin_amdgcn_mfma_f32_16x16x32_bf16(afh[m], bql[n], acc[m][n], 0, 0, 0);
        if constexpr (ASPLIT)
          acc[m][n] = __builtin_amdgcn_mfma_f32_16x16x32_bf16(afl[m], bqh[n], acc[m][n], 0, 0, 0);
      }
  };

  const int nkt = K >> 5;
  stage(0, 0);
  stage(1, 1);
  int cur = 0;
  for (int kt = 0; kt < nkt - 1; ++kt){
    asm volatile("s_waitcnt vmcnt(%0) lgkmcnt(0)" :: "i"(LPS) : "memory");
    __builtin_amdgcn_s_barrier();
    asm volatile("" ::: "memory");
    const int nx = (cur == 0) ? 2 : cur - 1;   // (cur+2)%3
    if (kt + 2 < nkt) stage(kt + 2, nx);
    compute(cur);
    cur = (cur == 2) ? 0 : cur + 1;
  }
  asm volatile("s_waitcnt vmcnt(0) lgkmcnt(0)" ::: "memory");
  __builtin_amdgcn_s_barrier();
  asm volatile("" ::: "memory");
  compute(cur);

#pragma unroll
  for (int m = 0; m < 4; ++m){
#pragma unroll
    for (int r = 0; r < 4; ++r){
      const int row = row0 + wr + m * 16 + kg * 4 + r;
      float rw0 = 0.f, rw1 = 0.f;
      if (EPI == EPI_G1){ rw0 = w01[2 * row]; rw1 = w01[2 * row + 1]; }
#pragma unroll
      for (int n = 0; n < 4; ++n){
        const int col = col0 + wc + n * 16 + r16;
        const size_t idx = (size_t)row * DD + col;
        float v = acc[m][n][r];
        if (EPI == EPI_G1){
          v += rw0 * bias[col] + rw1 * bias2[col];
          Ch[idx] = f2bf(v);                       // single bf16 (compL dropped)
        } else if (EPI == EPI_GELU_RES){
          v = gelu_f(v + bias[col]) + bf2f(resh[idx]);
          Ch[idx] = f2bf(v);                       // tbuf bf16
        } else if (EPI == EPI_GELU_SPLIT){
          v = gelu_f(v + bias[col]);
          const u16 h = f2bf(v);
          Ch[idx] = h; Cl[idx] = f2bf(v - bf2f(h));
        } else if (EPI == EPI_BIAS_SPLIT){
          v = v + bias[col];
          const u16 h = f2bf(v);
          Ch[idx] = h; Cl[idx] = f2bf(v - bf2f(h));
        } else { // EPI_F32
          Cf[idx] = v;
        }
      }
    }
  }
}

// ---------------- init: weight packing + vis split + small GEMVs -----------
// blocks [0,16128): pack weights; [16128,17664): vis split; [17664,18240): sdp
__global__ __launch_bounds__(256) void k_init(
    const float* __restrict__ lin_l, const float* __restrict__ lin_r,
    const float* __restrict__ inter_w, const float* __restrict__ ff1,
    const float* __restrict__ ff2, const float* __restrict__ ff4,
    const float* __restrict__ ff3,
    u16* __restrict__ WcH, u16* __restrict__ WcL,
    u16* __restrict__ WiH, u16* __restrict__ WiL,
    u16* __restrict__ Wf1H, u16* __restrict__ Wf1L,
    u16* __restrict__ Wf2H, u16* __restrict__ Wf2L,
    u16* __restrict__ Wf4H, u16* __restrict__ Wf4L,
    u16* __restrict__ Wf3TH, u16* __restrict__ Wf3TL,
    const float* __restrict__ ve, u16* __restrict__ visH, u16* __restrict__ visL,
    const float* __restrict__ same_emb, const float* __restrict__ den_emb,
    const float* __restrict__ ff1b, float* __restrict__ sdp)
{
  const int blk = blockIdx.x, t = threadIdx.x;
  if (blk < 16128){
    const int D2 = DD * DD;
    const int C0 = DD * 1536;
    const int i = blk * 256 + t;
    float v; u16 *ph, *pl;
    if (i < C0){
      int d = i / 1536, k = i - d * 1536;
      v = (k < DD) ? lin_l[d * DD + k] : lin_r[d * DD + (k - DD)];
      ph = WcH + i; pl = WcL + i;
    } else if (i < C0 + D2){ int j = i - C0;          v = inter_w[j]; ph = WiH + j;  pl = WiL + j; }
    else if (i < C0 + 2*D2){ int j = i - C0 - D2;     v = ff1[j];     ph = Wf1H + j; pl = Wf1L + j; }
    else if (i < C0 + 3*D2){ int j = i - C0 - 2*D2;   v = ff2[j];     ph = Wf2H + j; pl = Wf2L + j; }
    else if (i < C0 + 4*D2){ int j = i - C0 - 3*D2;   v = ff4[j];     ph = Wf4H + j; pl = Wf4L + j; }
    else { // i < C0 + 5*D2 (grid sized exactly)
      int j = i - C0 - 4*D2; int k = j / DD, d = j - k * DD;
      v = ff3[d * DD + k];  ph = Wf3TH + j; pl = Wf3TL + j;
    }
    const u16 h = f2bf(v);
    *ph = h; *pl = f2bf(v - bf2f(h));
  } else if (blk < 16128 + 1536){
    const int i = (blk - 16128) * 256 + t;       // [0, 393216)
    const float x = ve[i];
    const u16 h = f2bf(x);
    visH[i] = h; visL[i] = f2bf(x - bf2f(h));
  } else {
    // sdp[0]=(s0-s1)@ff1^T, sdp[1]=(d0-d1)@ff1^T, sdp[2]=(s1+d1)@ff1^T+b1
    const int j = (blk - 17664) * 4 + (t >> 6);  // [0, 2304)
    const int lane = t & 63;
    const int r = j / DD, jj = j - r * DD;
    const float* wr = ff1 + (size_t)jj * DD;
    float s = 0.f;
#pragma unroll
    for (int i = 0; i < 12; ++i){
      const int k = lane + i * 64;
      float x;
      if (r == 0)      x = same_emb[k] - same_emb[DD + k];
      else if (r == 1) x = den_emb[k] - den_emb[DD + k];
      else             x = same_emb[DD + k] + den_emb[DD + k];
      s += x * wr[k];
    }
#pragma unroll
    for (int off = 32; off; off >>= 1) s += __shfl_down(s, off, 64);
    if (lane == 0) sdp[j] = s + ((r == 2) ? ff1b[jj] : 0.f);
  }
}

__device__ __forceinline__ float block_sum256(float v, volatile float* sm){
#pragma unroll
  for (int off = 32; off; off >>= 1) v += __shfl_down(v, off, 64);
  const int lane = threadIdx.x & 63, wv = threadIdx.x >> 6;
  __syncthreads();
  if (lane == 0) sm[wv] = v;
  __syncthreads();
  return sm[0] + sm[1] + sm[2] + sm[3];
}

// per pair-row: attention dots, 2-way softmax, write w-scaled bf16 A rows.
// float4 (16B/lane); left/right boundary wave-aligned.
__global__ __launch_bounds__(256) void k_prep(const float* __restrict__ pt,
    const float* __restrict__ alw, const float* __restrict__ alb,
    const float* __restrict__ arw, const float* __restrict__ arb,
    u16* __restrict__ A1, float* __restrict__ w01)
{
  __shared__ float sm[4];
  const int r = blockIdx.x, t = threadIdx.x;
  const float4* row4 = (const float4*)(pt + (size_t)r * 1536);
  const float4* alw4 = (const float4*)alw;
  const float4* arw4 = (const float4*)arw;
  float wl = 0.f, wr = 0.f;
  const float4 x0 = row4[t];                 // f4 idx t: <192 left, else right
  if (t < 192){ const float4 w = alw4[t];
    wl += x0.x * w.x + x0.y * w.y + x0.z * w.z + x0.w * w.w; }
  else        { const float4 w = arw4[t - 192];
    wr += x0.x * w.x + x0.y * w.y + x0.z * w.z + x0.w * w.w; }
  float4 x1 = {0.f, 0.f, 0.f, 0.f};
  if (t < 128){
    x1 = row4[256 + t];                      // f4 idx 256+t: all right
    const float4 w = arw4[64 + t];
    wr += x1.x * w.x + x1.y * w.y + x1.z * w.z + x1.w * w.w;
  }
  wl = block_sum256(wl, sm);
  wr = block_sum256(wr, sm);
  wl += alb[0]; wr += arb[0];
  const float mx = fmaxf(wl, wr);
  const float e0 = expf(wl - mx), e1 = expf(wr - mx);
  const float inv = 1.f / (e0 + e1);
  const float w0 = e0 * inv, w1 = e1 * inv;
  ushort4* orow = (ushort4*)(A1 + (size_t)r * 1536);
  {
    const float s = (t < 192) ? w0 : w1;
    ushort4 o;
    o.x = f2bf(x0.x * s); o.y = f2bf(x0.y * s);
    o.z = f2bf(x0.z * s); o.w = f2bf(x0.w * s);
    orow[t] = o;
  }
  if (t < 128){
    ushort4 o;
    o.x = f2bf(x1.x * w1); o.y = f2bf(x1.y * w1);
    o.z = f2bf(x1.z * w1); o.w = f2bf(x1.w * w1);
    orow[256 + t] = o;
  }
  if (t == 0){ w01[2 * r] = w0; w01[2 * r + 1] = w1; }
}

// fused per-(b,s): LN + energy + softmax + span (LDS) + prep3 (rm_in split).
// tbuf bf16. span never hits HBM (only spanH/L for the OUT gemm).
__global__ __launch_bounds__(256) void k_lnprep(const u16* __restrict__ tbuf,
    const float* __restrict__ g, const float* __restrict__ bb,
    const float* __restrict__ ew,
    const float* __restrict__ vis_emb, const float* __restrict__ pairs_den,
    u16* __restrict__ spanH, u16* __restrict__ spanL,
    u16* __restrict__ rmInH, u16* __restrict__ rmInL)
{
  __shared__ float smu[32], srs[32], se[32];
  __shared__ float sspan[DD];
  const int bs = blockIdx.x, t = threadIdx.x;
  const int lane = t & 63, wv = t >> 6;
  const u16* xb = tbuf + (size_t)bs * 32 * DD;
  const float4* g4 = (const float4*)g;
  const float4* b4 = (const float4*)bb;
  const float4* e4 = (const float4*)ew;
  for (int r = wv * 8; r < wv * 8 + 8; ++r){
    const ushort4* xr4 = (const ushort4*)(xb + (size_t)r * DD);
    float4 x4[3]; float s = 0.f, q = 0.f;
#pragma unroll
    for (int j = 0; j < 3; ++j){
      const ushort4 u = xr4[lane * 3 + j];
      float4 v; v.x = bf2f(u.x); v.y = bf2f(u.y); v.z = bf2f(u.z); v.w = bf2f(u.w);
      x4[j] = v;
      s += v.x + v.y + v.z + v.w;
      q += v.x * v.x + v.y * v.y + v.z * v.z + v.w * v.w;
    }
#pragma unroll
    for (int off = 1; off < 64; off <<= 1){ s += __shfl_xor(s, off, 64); q += __shfl_xor(q, off, 64); }
    const float mu = s * (1.f / 768.f);
    const float var = q * (1.f / 768.f) - mu * mu;
    const float rs = rsqrtf(var + 1e-12f);
    float e = 0.f;
#pragma unroll
    for (int j = 0; j < 3; ++j){
      const float4 gv = g4[lane * 3 + j], bv = b4[lane * 3 + j], wv4 = e4[lane * 3 + j];
      e += ((x4[j].x - mu) * rs * gv.x + bv.x) * wv4.x
         + ((x4[j].y - mu) * rs * gv.y + bv.y) * wv4.y
         + ((x4[j].z - mu) * rs * gv.z + bv.z) * wv4.z
         + ((x4[j].w - mu) * rs * gv.w + bv.w) * wv4.w;
    }
#pragma unroll
    for (int off = 1; off < 64; off <<= 1) e += __shfl_xor(e, off, 64);
    if (lane == 0){ smu[r] = mu; srs[r] = rs; se[r] = e; }
  }
  __syncthreads();
  float mx = -3.4e38f;
#pragma unroll
  for (int n = 0; n < 32; ++n) mx = fmaxf(mx, se[n]);
  float a[32]; float Z = 0.f;
#pragma unroll
  for (int n = 0; n < 32; ++n){ a[n] = expf(se[n] - mx); Z += a[n]; }
  const float inv = 1.f / Z;
  if (t < 192){
    const float4 gv = g4[t], bv = b4[t];
    float4 acc = {0.f, 0.f, 0.f, 0.f};
    for (int n = 0; n < 32; ++n){
      const float an = a[n] * inv, mun = smu[n], rsn = srs[n];
      const ushort4 u = ((const ushort4*)(xb + (size_t)n * DD))[t];
      acc.x += an * ((bf2f(u.x) - mun) * rsn * gv.x + bv.x);
      acc.y += an * ((bf2f(u.y) - mun) * rsn * gv.y + bv.y);
      acc.z += an * ((bf2f(u.z) - mun) * rsn * gv.z + bv.z);
      acc.w += an * ((bf2f(u.w) - mun) * rsn * gv.w + bv.w);
    }
    ((float4*)sspan)[t] = acc;
    ushort4 h, l;
    h.x = f2bf(acc.x); l.x = f2bf(acc.x - bf2f(h.x));
    h.y = f2bf(acc.y); l.y = f2bf(acc.y - bf2f(h.y));
    h.z = f2bf(acc.z); l.z = f2bf(acc.z - bf2f(h.z));
    h.w = f2bf(acc.w); l.w = f2bf(acc.w - bf2f(h.w));
    ((ushort4*)(spanH + (size_t)bs * DD))[t] = h;
    ((ushort4*)(spanL + (size_t)bs * DD))[t] = l;
  }
  __syncthreads();
  // prep3: rm_in = right_vis + span (split)
  const int b = bs >> 7;
  const float* rd = pairs_den + (size_t)bs * 128 + 64;
  const float* ve = vis_emb + (size_t)b * 64 * DD;
  float rv[3] = {0.f, 0.f, 0.f};
  for (int o = 0; o < 64; ++o){
    const float w = rd[o];
#pragma unroll
    for (int j = 0; j < 3; ++j) rv[j] += w * ve[o * DD + t + j * 256];
  }
#pragma unroll
  for (int j = 0; j < 3; ++j){
    const int c = t + j * 256;
    const float v = rv[j] + sspan[c];
    const u16 h = f2bf(v);
    rmInH[(size_t)bs * DD + c] = h;
    rmInL[(size_t)bs * DD + c] = f2bf(v - bf2f(h));
  }
}

// fused final (c-dot inlined as block-wide prologue)
__global__ __launch_bounds__(256) void k_dot(const float* __restrict__ VE1,
    const float* __restrict__ MQ1, const float* __restrict__ sdp,
    const float* __restrict__ rproj, const u16* __restrict__ rtMH,
    const u16* __restrict__ rtML, const float* __restrict__ ff3_b,
    const float* __restrict__ pairs_den, const float* __restrict__ obj_mask,
    float* __restrict__ out)
{
  __shared__ float sm[4];
  const int bs = blockIdx.x;
  const int b = bs >> 7;
  const int t = threadIdx.x, lane = t & 63, wv = t >> 6;
  float cp = 0.f;
#pragma unroll
  for (int j = 0; j < 3; ++j){
    const int d = t + j * 256;
    cp += (bf2f(rtMH[(size_t)bs * DD + d]) + bf2f(rtML[(size_t)bs * DD + d])) * ff3_b[d];
  }
  const float cb = block_sum256(cp, sm);
  float mqc[12], rp[12], d1[12], d2[12];
#pragma unroll
  for (int i = 0; i < 12; ++i){
    const int idx = lane + i * 64;
    mqc[i] = MQ1[(size_t)bs * DD + idx] + sdp[2 * DD + idx];
    rp[i]  = rproj[(size_t)bs * DD + idx];
    d1[i]  = sdp[idx];
    d2[i]  = sdp[DD + idx];
  }
  const float* ldp = pairs_den + (size_t)bs * 128;
  for (int oi = 0; oi < 16; ++oi){
    const int o = wv * 16 + oi;
    const float ld = ldp[o], rd = ldp[64 + o];
    const float* ve = VE1 + ((size_t)(b * 64 + o)) * DD;
    float s = 0.f;
#pragma unroll
    for (int i = 0; i < 12; ++i){
      const float q = ve[lane + i * 64] + mqc[i] + rd * d1[i] + ld * d2[i];
      s += gelu_f(q) * rp[i];
    }
#pragma unroll
    for (int off = 1; off < 64; off <<= 1) s += __shfl_xor(s, off, 64);
    if (lane == 0){
      const float logit = s + cb;
      out[bs * 64 + o] = obj_mask[b * 64 + o] / (1.f + expf(-logit));
    }
  }
}

extern "C" void kernel_launch(void* const* d_in, const int* in_sizes, int n_in,
                              void* d_out, int out_size, void* d_ws, size_t ws_size,
                              hipStream_t stream)
{
  const float* pairs_text = (const float*)d_in[0];
  const float* vis_emb    = (const float*)d_in[1];
  const float* pairs_den  = (const float*)d_in[2];
  const float* obj_mask   = (const float*)d_in[3];
  const float* att_l_w = (const float*)d_in[4];
  const float* att_l_b = (const float*)d_in[5];
  const float* att_r_w = (const float*)d_in[6];
  const float* att_r_b = (const float*)d_in[7];
  const float* lin_l_w = (const float*)d_in[8];
  const float* lin_l_b = (const float*)d_in[9];
  const float* lin_r_w = (const float*)d_in[10];
  const float* lin_r_b = (const float*)d_in[11];
  const float* inter_w = (const float*)d_in[12];
  const float* inter_b = (const float*)d_in[13];
  const float* ln_g = (const float*)d_in[14];
  const float* ln_b = (const float*)d_in[15];
  const float* energy_w = (const float*)d_in[16];
  const float* ff1_w = (const float*)d_in[18];
  const float* ff1_b = (const float*)d_in[19];
  const float* ff2_w = (const float*)d_in[20];
  const float* ff2_b = (const float*)d_in[21];
  const float* ff3_w = (const float*)d_in[22];
  const float* ff3_b = (const float*)d_in[23];
  const float* ff4_w = (const float*)d_in[24];
  const float* ff4_b = (const float*)d_in[25];
  const float* same_emb = (const float*)d_in[26];
  const float* den_emb  = (const float*)d_in[27];

  char* base = (char*)d_ws;
  size_t off = 0;
  auto alloc = [&](size_t bytes) -> void* {
    void* p = base + off;
    off += (bytes + 255) & ~(size_t)255;
    return p;
  };
  // Region A (100.66 MB): A1_hi -> tbuf(bf16, 50MB)
  char* RA = (char*)alloc((size_t)R1 * 1536 * 2);
  // Region B (50.33 MB): compH (live G1..G2)
  char* RB = (char*)alloc((size_t)R1 * DD * 2);
  float* w01  = (float*)alloc((size_t)R1 * 2 * 4);
  u16* WcH  = (u16*)alloc((size_t)DD * 1536 * 2);
  u16* WcL  = (u16*)alloc((size_t)DD * 1536 * 2);
  u16* WiH  = (u16*)alloc((size_t)DD * DD * 2);
  u16* WiL  = (u16*)alloc((size_t)DD * DD * 2);
  u16* Wf1H = (u16*)alloc((size_t)DD * DD * 2);
  u16* Wf1L = (u16*)alloc((size_t)DD * DD * 2);
  u16* Wf2H = (u16*)alloc((size_t)DD * DD * 2);
  u16* Wf2L = (u16*)alloc((size_t)DD * DD * 2);
  u16* Wf4H = (u16*)alloc((size_t)DD * DD * 2);
  u16* Wf4L = (u16*)alloc((size_t)DD * DD * 2);
  u16* Wf3TH = (u16*)alloc((size_t)DD * DD * 2);
  u16* Wf3TL = (u16*)alloc((size_t)DD * DD * 2);
  // cmb (1536 rows = vis 512 + span 1024) + OUT + sdp: own storage (no alias)
  u16*   cmbH = (u16*)alloc((size_t)1536 * DD * 2);
  u16*   cmbL = (u16*)alloc((size_t)1536 * DD * 2);
  float* OUT  = (float*)alloc((size_t)1536 * DD * 4);
  float* sdp  = (float*)alloc((size_t)3 * DD * 4);
  u16* rmInH   = (u16*)alloc((size_t)NBS * DD * 2);
  u16* rmInL   = (u16*)alloc((size_t)NBS * DD * 2);
  u16* rm1H    = (u16*)alloc((size_t)NBS * DD * 2);
  u16* rm1L    = (u16*)alloc((size_t)NBS * DD * 2);
  u16* rtMH    = (u16*)alloc((size_t)NBS * DD * 2);
  u16* rtML    = (u16*)alloc((size_t)NBS * DD * 2);
  float* rproj = (float*)alloc((size_t)NBS * DD * 4);

  u16*   A1h   = (u16*)RA;            // live: k_prep..G1
  u16*   tbuf  = (u16*)RA;            // live: G2..k_lnprep (bf16, 50MB)
  u16*   compH = (u16*)RB;            // live: G1..G2 (50MB)
  u16*   spanH = cmbH + (size_t)512 * DD;
  u16*   spanL = cmbL + (size_t)512 * DD;
  float* VE1   = OUT;
  float* MQ1   = OUT + (size_t)512 * DD;

  k_init<<<18240, 256, 0, stream>>>(lin_l_w, lin_r_w, inter_w, ff1_w, ff2_w, ff4_w, ff3_w,
                                    WcH, WcL, WiH, WiL, Wf1H, Wf1L, Wf2H, Wf2L,
                                    Wf4H, Wf4L, Wf3TH, Wf3TL,
                                    vis_emb, cmbH, cmbL,
                                    same_emb, den_emb, ff1_b, sdp);
  k_prep<<<R1, 256, 0, stream>>>(pairs_text, att_l_w, att_l_b, att_r_w, att_r_b, A1h, w01);
  gemm_bt<EPI_G1, 0, 0><<<6 * (R1 / 128), 256, 0, stream>>>(
      A1h, nullptr, 1536, WcH, nullptr, 1536, compH, nullptr, nullptr,
      lin_l_b, w01, lin_r_b, nullptr);
  gemm_bt<EPI_GELU_RES, 0, 0><<<6 * (R1 / 128), 256, 0, stream>>>(
      compH, nullptr, DD, WiH, nullptr, DD, tbuf, nullptr, nullptr,
      inter_b, nullptr, nullptr, compH);
  k_lnprep<<<NBS, 256, 0, stream>>>(tbuf, ln_g, ln_b, energy_w,
                                    vis_emb, pairs_den,
                                    spanH, spanL, rmInH, rmInL);
  // merged VE1+MQ1: [vis(512); span(1024)] @ ff1^T, M=1536
  gemm_bt<EPI_F32, 1, 1><<<6 * (1536 / 128), 256, 0, stream>>>(
      cmbH, cmbL, DD, Wf1H, Wf1L, DD, nullptr, nullptr, OUT,
      nullptr, nullptr, nullptr, nullptr);
  gemm_bt<EPI_GELU_SPLIT, 1, 1><<<6 * (NBS / 128), 256, 0, stream>>>(
      rmInH, rmInL, DD, Wf2H, Wf2L, DD, rm1H, rm1L, nullptr,
      ff2_b, nullptr, nullptr, nullptr);
  gemm_bt<EPI_BIAS_SPLIT, 1, 1><<<6 * (NBS / 128), 256, 0, stream>>>(
      rm1H, rm1L, DD, Wf4H, Wf4L, DD, rtMH, rtML, nullptr,
      ff4_b, nullptr, nullptr, nullptr);
  gemm_bt<EPI_F32, 1, 1><<<6 * (NBS / 128), 256, 0, stream>>>(
      rtMH, rtML, DD, Wf3TH, Wf3TL, DD, nullptr, nullptr, rproj,
      nullptr, nullptr, nullptr, nullptr);
  k_dot<<<NBS, 256, 0, stream>>>(VE1, MQ1, sdp, rproj, rtMH, rtML, ff3_b,
                                 pairs_den, obj_mask, (float*)d_out);
}